// Round 1
// baseline (711.045 us; speedup 1.0000x reference)
//
#include <hip/hip_runtime.h>

// (B,S,D,K,F) = (4, 2048, 1024, 4, 4096)
static constexpr int Bb = 4;
static constexpr int Ss = 2048;
static constexpr int Dd = 1024;
static constexpr int Ff = 4096;
static constexpr int Mm = Bb * Ss;              // 8192 rows
static constexpr size_t ND = (size_t)Mm * Dd;   // 8388608
static constexpr int CH = 32;                   // scan chunks
static constexpr int CL = Ss / CH;              // chunk length 64

typedef __attribute__((ext_vector_type(8))) short short8;
typedef __attribute__((ext_vector_type(4))) float floatx4;

__device__ __forceinline__ unsigned f2bf(float f) {
  unsigned u = __builtin_bit_cast(unsigned, f);
  return (u + 0x7FFFu + ((u >> 16) & 1u)) >> 16;   // RNE
}
__device__ __forceinline__ float bf2f(unsigned bits) {
  return __builtin_bit_cast(float, bits << 16);
}
__device__ __forceinline__ void gload_lds16(const void* g, void* lds) {
  __builtin_amdgcn_global_load_lds((const __attribute__((address_space(1))) void*)g,
                                   (__attribute__((address_space(3))) void*)lds,
                                   16, 0, 0);
}
// fast sigmoid / tanh-gelu via hw v_exp_f32 + v_rcp_f32 (f32-accurate ~1e-6)
__device__ __forceinline__ float fsig(float x) {
  return __builtin_amdgcn_rcpf(1.0f + __expf(-x));
}
__device__ __forceinline__ float fgelu(float v) {
  float z = 1.5957691216057308f * fmaf(0.044715f * v, v * v, v);
  return v * __builtin_amdgcn_rcpf(1.0f + __expf(-z));
}

// ---------------- weight transpose + fp32->bf16: W[K][N] -> WT[N][K] --------
__global__ __launch_bounds__(256) void wconv_k(const float* __restrict__ W,
                                               unsigned short* __restrict__ WT,
                                               int K, int N) {
  __shared__ float tile[32][33];
  int tx = threadIdx.x & 31, ty = threadIdx.x >> 5;
  int bx = blockIdx.x * 32, by = blockIdx.y * 32;
#pragma unroll
  for (int i = 0; i < 32; i += 8)
    tile[ty + i][tx] = W[(size_t)(by + ty + i) * N + bx + tx];
  __syncthreads();
#pragma unroll
  for (int i = 0; i < 32; i += 8)
    WT[(size_t)(bx + ty + i) * K + by + tx] = (unsigned short)f2bf(tile[tx][ty + i]);
}

// ---------------- RMSNorm: fp32 in, bf16 out --------------------------------
__global__ __launch_bounds__(256) void rmsnorm_bf_k(const float* __restrict__ x,
                                                    const float* __restrict__ w,
                                                    unsigned short* __restrict__ out) {
  int row = blockIdx.x;
  const float4* xr = (const float4*)(x + (size_t)row * Dd);
  int t = threadIdx.x;
  float4 v = xr[t];
  float ss = v.x * v.x + v.y * v.y + v.z * v.z + v.w * v.w;
#pragma unroll
  for (int off = 32; off > 0; off >>= 1) ss += __shfl_down(ss, off, 64);
  __shared__ float sb[4];
  if ((t & 63) == 0) sb[t >> 6] = ss;
  __syncthreads();
  float tot = sb[0] + sb[1] + sb[2] + sb[3];
  float sc = rsqrtf(tot * (1.0f / (float)Dd) + 1e-6f);
  float4 wv = ((const float4*)w)[t];
  unsigned lo = f2bf(v.x * sc * wv.x) | (f2bf(v.y * sc * wv.y) << 16);
  unsigned hi = f2bf(v.z * sc * wv.z) | (f2bf(v.w * sc * wv.w) << 16);
  *(uint2*)(out + (size_t)row * Dd + t * 4) = make_uint2(lo, hi);
}

// ---------------- Causal depthwise conv (bf16 in/out) -> concat[:,0:D] ------
__global__ __launch_bounds__(256) void conv_k(const unsigned short* __restrict__ xn,
                                              const float* __restrict__ kern,
                                              const float* __restrict__ bias,
                                              unsigned short* __restrict__ outC) {
  size_t q = (size_t)blockIdx.x * 256 + threadIdx.x;  // over ND/4
  size_t i = q * 4;
  int d = (int)(i & (Dd - 1));
  int m = (int)(i >> 10);
  int t = m & (Ss - 1);
  float acc[4];
#pragma unroll
  for (int j = 0; j < 4; j++) acc[j] = bias[d + j];
#pragma unroll
  for (int k = 0; k < 4; k++) {
    if (t >= k) {
      uint2 xv = *(const uint2*)(xn + i - (size_t)k * Dd);
      float x0 = bf2f(xv.x & 0xFFFF), x1 = bf2f(xv.x >> 16);
      float x2 = bf2f(xv.y & 0xFFFF), x3 = bf2f(xv.y >> 16);
      acc[0] = fmaf(kern[(d + 0) * 4 + k], x0, acc[0]);
      acc[1] = fmaf(kern[(d + 1) * 4 + k], x1, acc[1]);
      acc[2] = fmaf(kern[(d + 2) * 4 + k], x2, acc[2]);
      acc[3] = fmaf(kern[(d + 3) * 4 + k], x3, acc[3]);
    }
  }
  unsigned lo = f2bf(acc[0]) | (f2bf(acc[1]) << 16);
  unsigned hi = f2bf(acc[2]) | (f2bf(acc[3]) << 16);
  *(uint2*)(outC + (size_t)m * (2 * Dd) + d) = make_uint2(lo, hi);
}

// ---------------- bf16 MFMA GEMM v2: C[M,N] = A[M,K] @ BT[N,K]^T ------------
// BM=256, BN=128, BK=64. 512 threads = 8 waves (4M x 2N), per-wave 64x64,
// 4x4 16x16x32 MFMA subtiles (identical fragment/epilogue geometry to the
// verified 646us kernel -- arithmetic is unchanged, only tiling/schedule).
// Schedule: triple-buffered LDS ring (144 KiB, 1 block/CU), stage tile t+2
// while computing tile t -> counted s_waitcnt vmcnt(6) at tile boundaries
// (never 0 in steady state; T4). 4 phases per K-tile, 8 MFMA each, raw
// s_barriers + setprio(1) around MFMA (T3/T5). LDS XOR-swizzle on 16B blocks
// (blk ^= row&7; T2) applied both sides: linear global_load_lds dest +
// pre-permuted per-lane global source (coalescing preserved: permutation
// stays within each 128B row) + XOR on ds_read_b128 address.
// MODE bits: 1=+bias[col], 2=gelu, 4=+extra (fp32), 8=bf16 out, 16=velocity
template <int MODE>
__global__ __launch_bounds__(512, 2) void bgemm2_k(const unsigned short* __restrict__ A,
                                                   const unsigned short* __restrict__ BT,
                                                   void* __restrict__ Cout,
                                                   int M, int N, int K,
                                                   const float* __restrict__ bias,
                                                   const float* __restrict__ extra,
                                                   const float* __restrict__ vel_in,
                                                   const float* __restrict__ x_in,
                                                   const float* __restrict__ log_beta,
                                                   float* __restrict__ vel_out) {
  __shared__ unsigned short As[3][256 * 64];   // 96 KiB
  __shared__ unsigned short Bs[3][128 * 64];   // 48 KiB
  const int tid = threadIdx.x;
  const int wid = tid >> 6, lane = tid & 63;
  const int wm = wid >> 1, wn = wid & 1;       // 4M x 2N wave grid
  const int r = lane & 15, quad = lane >> 4, r7 = lane & 7;
  const int bm = blockIdx.y * 256, bn = blockIdx.x * 128;
  const int NT = K >> 6;                        // K-tiles of 64 (>= 16 here)

  // ---- staging geometry: 1 KiB wave-chunks = 8 rows x 128B; A 32 chunks
  // (wave w -> chunks w*4+c), B 16 chunks (w*2+c). Per-lane source block is
  // pre-swizzled so that linear LDS placement == swizzled layout.
  const int lrow = lane >> 3;                  // row within 8-row chunk
  const int sblk = (lane & 7) ^ lrow;          // pre-swizzled 16B block index
  const unsigned short* Asrc = A  + (size_t)(bm + wid * 32 + lrow) * K + sblk * 8;
  const unsigned short* Bsrc = BT + (size_t)(bn + wid * 16 + lrow) * K + sblk * 8;

  // ---- fragment-read addressing (element offsets, swizzled k-block)
  const int aBase = (wm * 64 + r) * 64;
  const int bBase = (wn * 64 + r) * 64;
  const int kq0 = ((quad) ^ r7) * 8;           // ks=0 : blocks 0..3 ^ row&7
  const int kq1 = ((4 + quad) ^ r7) * 8;       // ks=1 : blocks 4..7 ^ row&7

  floatx4 acc[4][4];
#pragma unroll
  for (int i = 0; i < 4; i++)
#pragma unroll
    for (int j = 0; j < 4; j++) acc[i][j] = (floatx4){0.f, 0.f, 0.f, 0.f};

#define STG_A(bq, k0, c) gload_lds16(Asrc + (size_t)(c) * 8 * K + (k0), (void*)&As[bq][(wid * 4 + (c)) * 512])
#define STG_B(bq, k0, c) gload_lds16(Bsrc + (size_t)(c) * 8 * K + (k0), (void*)&Bs[bq][(wid * 2 + (c)) * 512])
#define LD_A(i, ks) aF[i][ks] = *(const short8*)&Ab[aBase + (i) * 1024 + ((ks) ? kq1 : kq0)]
#define LD_B(j, ks) bF[j][ks] = *(const short8*)&Bbuf[bBase + (j) * 1024 + ((ks) ? kq1 : kq0)]
#define MFMA4(i, j)                                                                         \
  acc[i][j] = __builtin_amdgcn_mfma_f32_16x16x32_bf16(bF[j][0], aF[i][0], acc[i][j], 0, 0, 0); \
  acc[i][j] = __builtin_amdgcn_mfma_f32_16x16x32_bf16(bF[j][1], aF[i][1], acc[i][j], 0, 0, 0)

  // ---- prologue: stage tiles 0 and 1 (12 loads/thread), wait for tile 0
  STG_A(0, 0, 0); STG_A(0, 0, 1); STG_A(0, 0, 2); STG_A(0, 0, 3);
  STG_B(0, 0, 0); STG_B(0, 0, 1);
  STG_A(1, 64, 0); STG_A(1, 64, 1); STG_A(1, 64, 2); STG_A(1, 64, 3);
  STG_B(1, 64, 0); STG_B(1, 64, 1);
  asm volatile("s_waitcnt vmcnt(6)" ::: "memory");
  __builtin_amdgcn_s_barrier();
  asm volatile("" ::: "memory");
  __builtin_amdgcn_sched_barrier(0);

  for (int t = 0; t < NT; ++t) {
    const unsigned short* Ab = &As[t % 3][0];
    const unsigned short* Bbuf = &Bs[t % 3][0];
    const int pf = (t + 2 < NT);                // prefetch tile t+2 exists
    const int pbuf = (t + 2) % 3;
    const int pk0 = (t + 2) * 64;
    short8 aF[4][2], bF[4][2];

    // -- phase 0: reads A(i0,i1)+B(j0,j1); stage A c0,c1; MFMA quad (i01,j01)
    if (pf) { STG_A(pbuf, pk0, 0); STG_A(pbuf, pk0, 1); }
    LD_A(0, 0); LD_A(0, 1); LD_A(1, 0); LD_A(1, 1);
    LD_B(0, 0); LD_B(0, 1); LD_B(1, 0); LD_B(1, 1);
    __builtin_amdgcn_s_barrier();
    __builtin_amdgcn_s_setprio(1);
    MFMA4(0, 0); MFMA4(0, 1); MFMA4(1, 0); MFMA4(1, 1);
    __builtin_amdgcn_s_setprio(0);
    __builtin_amdgcn_s_barrier();

    // -- phase 1: reads B(j2,j3); stage A c2,c3; MFMA quad (i01,j23)
    if (pf) { STG_A(pbuf, pk0, 2); STG_A(pbuf, pk0, 3); }
    LD_B(2, 0); LD_B(2, 1); LD_B(3, 0); LD_B(3, 1);
    __builtin_amdgcn_s_barrier();
    __builtin_amdgcn_s_setprio(1);
    MFMA4(0, 2); MFMA4(0, 3); MFMA4(1, 2); MFMA4(1, 3);
    __builtin_amdgcn_s_setprio(0);
    __builtin_amdgcn_s_barrier();

    // -- phase 2: reads A(i2,i3); stage B c0; MFMA quad (i23,j01)
    if (pf) { STG_B(pbuf, pk0, 0); }
    LD_A(2, 0); LD_A(2, 1); LD_A(3, 0); LD_A(3, 1);
    __builtin_amdgcn_s_barrier();
    __builtin_amdgcn_s_setprio(1);
    MFMA4(2, 0); MFMA4(2, 1); MFMA4(3, 0); MFMA4(3, 1);
    __builtin_amdgcn_s_setprio(0);
    __builtin_amdgcn_s_barrier();

    // -- phase 3: stage B c1; MFMA quad (i23,j23)
    if (pf) { STG_B(pbuf, pk0, 1); }
    __builtin_amdgcn_s_setprio(1);
    MFMA4(2, 2); MFMA4(2, 3); MFMA4(3, 2); MFMA4(3, 3);
    __builtin_amdgcn_s_setprio(0);

    // -- tile boundary: counted wait for tile t+1's staging, then converge.
    if (t + 1 < NT) {
      if (pf) asm volatile("s_waitcnt vmcnt(6)" ::: "memory");
      else    asm volatile("s_waitcnt vmcnt(0)" ::: "memory");
      __builtin_amdgcn_s_barrier();
      asm volatile("" ::: "memory");
      __builtin_amdgcn_sched_barrier(0);
    }
  }
#undef STG_A
#undef STG_B
#undef LD_A
#undef LD_B
#undef MFMA4

  // acc[i][j][0..3] = C[row = bm+wm*64+i*16+r][col = bn+wn*64+j*16+quad*4 +0..3]
#pragma unroll
  for (int i = 0; i < 4; i++) {
    int rowg = bm + wm * 64 + i * 16 + r;
#pragma unroll
    for (int j = 0; j < 4; j++) {
      int colg = bn + wn * 64 + j * 16 + quad * 4;
      size_t idx = (size_t)rowg * N + colg;
      float v0 = acc[i][j][0], v1 = acc[i][j][1], v2 = acc[i][j][2], v3 = acc[i][j][3];
      if (MODE & 1) {
        float4 bv = *(const float4*)(bias + colg);
        v0 += bv.x; v1 += bv.y; v2 += bv.z; v3 += bv.w;
      }
      if (MODE & 2) {
        v0 = fgelu(v0); v1 = fgelu(v1); v2 = fgelu(v2); v3 = fgelu(v3);
      }
      if (MODE & 4) {
        float4 ev = *(const float4*)(extra + idx);
        v0 += ev.x; v1 += ev.y; v2 += ev.z; v3 += ev.w;
      }
      if (MODE & 16) {
        float4 lb = *(const float4*)(log_beta + colg);
        float4 vi = *(const float4*)(vel_in + idx);
        float4 xi = *(const float4*)(x_in + idx);
        float4 vn;
        vn.x = fmaf(fsig(lb.x), vi.x, v0);
        vn.y = fmaf(fsig(lb.y), vi.y, v1);
        vn.z = fmaf(fsig(lb.z), vi.z, v2);
        vn.w = fmaf(fsig(lb.w), vi.w, v3);
        *(float4*)(vel_out + idx) = vn;
        v0 = xi.x + vn.x; v1 = xi.y + vn.y; v2 = xi.z + vn.z; v3 = xi.w + vn.w;
      }
      if (MODE & 8) {
        uint2 pk;
        pk.x = f2bf(v0) | (f2bf(v1) << 16);
        pk.y = f2bf(v2) | (f2bf(v3) << 16);
        *(uint2*)((unsigned short*)Cout + idx) = pk;
      } else {
        float4 o; o.x = v0; o.y = v1; o.z = v2; o.w = v3;
        *(float4*)((float*)Cout + idx) = o;
      }
    }
  }
}

// ---------------- scan phase 1: gating + per-chunk (A, h_local) -------------
__global__ __launch_bounds__(256) void scan_p1(const unsigned short* __restrict__ gapre,
                                               const unsigned short* __restrict__ xn,
                                               const float* __restrict__ lam,
                                               unsigned short* __restrict__ ub,
                                               float* __restrict__ carryA,
                                               float* __restrict__ carryH) {
  int g = blockIdx.x * 256 + threadIdx.x;    // 0..131071
  int e = g & (Dd - 1);
  int bc = g >> 10;
  int b = bc & 3;
  int c = bc >> 2;
  float l = lam[e];
  float sp = fmaxf(l, 0.0f) + log1pf(__expf(-fabsf(l)));
  float m8sp = -8.0f * sp;
  size_t m0 = (size_t)b * Ss + (size_t)c * CL;
  float A = 1.0f, h = 0.0f;
#pragma unroll 4
  for (int t = 0; t < CL; t++) {
    size_t m = m0 + t;
    float gp = bf2f(gapre[m * 2048 + e]);
    float ap = bf2f(gapre[m * 2048 + 1024 + e]);
    float xv = bf2f(xn[m * Dd + e]);
    float a = __expf(m8sp * fsig(ap));
    float u = sqrtf(fmaxf(1.0f - a * a, 0.0f)) * fsig(gp) * xv;
    ub[m * Dd + e] = (unsigned short)f2bf(u);
    A *= a;
    h = fmaf(a, h, u);
  }
  carryA[c * 4096 + b * 1024 + e] = A;
  carryH[c * 4096 + b * 1024 + e] = h;
}

// ---------------- scan phase 2: scan carries -> per-chunk init state --------
__global__ __launch_bounds__(256) void scan_p2(const float* __restrict__ carryA,
                                               const float* __restrict__ carryH,
                                               float* __restrict__ init) {
  int ch = blockIdx.x * 256 + threadIdx.x;   // 0..4095
  float H = 0.0f;
#pragma unroll
  for (int c = 0; c < CH; c++) {
    init[c * 4096 + ch] = H;
    H = fmaf(carryA[c * 4096 + ch], H, carryH[c * 4096 + ch]);
  }
}

// ---------------- scan phase 3: rescan chunk with init -> concat[:,D:2D] ----
__global__ __launch_bounds__(256) void scan_p3(const unsigned short* __restrict__ gapre,
                                               const unsigned short* __restrict__ ub,
                                               const float* __restrict__ lam,
                                               const float* __restrict__ init,
                                               unsigned short* __restrict__ outC) {
  int g = blockIdx.x * 256 + threadIdx.x;
  int e = g & (Dd - 1);
  int bc = g >> 10;
  int b = bc & 3;
  int c = bc >> 2;
  float l = lam[e];
  float sp = fmaxf(l, 0.0f) + log1pf(__expf(-fabsf(l)));
  float m8sp = -8.0f * sp;
  size_t m0 = (size_t)b * Ss + (size_t)c * CL;
  float h = init[c * 4096 + b * 1024 + e];
#pragma unroll 4
  for (int t = 0; t < CL; t++) {
    size_t m = m0 + t;
    float ap = bf2f(gapre[m * 2048 + 1024 + e]);
    float a = __expf(m8sp * fsig(ap));
    float u = bf2f(ub[m * Dd + e]);
    h = fmaf(a, h, u);
    outC[m * (2 * Dd) + Dd + e] = (unsigned short)f2bf(h);
  }
}

extern "C" void kernel_launch(void* const* d_in, const int* in_sizes, int n_in,
                              void* d_out, int out_size, void* d_ws, size_t ws_size,
                              hipStream_t stream) {
  const float* x        = (const float*)d_in[0];
  const float* velocity = (const float*)d_in[1];
  const float* pre_w    = (const float*)d_in[2];
  const float* conv_w   = (const float*)d_in[3];
  const float* conv_b   = (const float*)d_in[4];
  const float* W_gate   = (const float*)d_in[5];
  const float* W_a      = (const float*)d_in[6];
  const float* lam      = (const float*)d_in[7];
  const float* W_out    = (const float*)d_in[8];
  const float* b_out    = (const float*)d_in[9];
  const float* log_beta = (const float*)d_in[10];
  const float* ffn_w    = (const float*)d_in[11];
  const float* W_ff1    = (const float*)d_in[12];
  const float* b_ff1    = (const float*)d_in[13];
  const float* W_ff2    = (const float*)d_in[14];
  const float* b_ff2    = (const float*)d_in[15];

  float* out0 = (float*)d_out;
  float* out1 = out0 + ND;

  // ---- workspace (byte offsets), lifetime-aliased; peak 152 MB ----
  const size_t MB = 1024 * 1024;
  char* ws = (char*)d_ws;
  unsigned short* WgaT  = (unsigned short*)ws;               // 2048x1024 [0,4) (gate|a)
  unsigned short* WoT   = WgaT + (size_t)2 * 1024 * 1024;    // [4,8)
  unsigned short* Wf1T  = WoT + (size_t)2 * 1024 * 1024;     // [8,16)
  unsigned short* Wf2T  = Wf1T + (size_t)4 * 1024 * 1024;    // [16,24)
  float*          mixer = (float*)(ws + 24 * MB);            // 32 MB [24,56) — x_new
  float*          carA  = (float*)(ws + 24 * MB);            // overlay (pre-step-6)
  float*          carH  = (float*)(ws + 24 * MB + 512 * 1024);
  float*          initb = (float*)(ws + 25 * MB);
  unsigned short* conc  = (unsigned short*)(ws + 56 * MB);   // 32 MB [56,88)
  unsigned short* gapre = (unsigned short*)(ws + 88 * MB);   // 32 MB [88,120)
  unsigned short* xnbf  = (unsigned short*)(ws + 120 * MB);  // 16 MB [120,136)
  unsigned short* ubf   = (unsigned short*)(ws + 136 * MB);  // 16 MB [136,152)
  unsigned short* midbf = (unsigned short*)(ws + 88 * MB);   // 64 MB overlay [88,152)
  unsigned short* nrmbf = (unsigned short*)(ws + 56 * MB);   // overlay conc

  const int EB = 256;
  const int egrid4 = (int)(ND / 4 / EB);

  // 0. weight transpose + bf16 convert (gate|a combined, contiguous)
  wconv_k<<<dim3(32, 32),  256, 0, stream>>>(W_gate, WgaT, 1024, 1024);
  wconv_k<<<dim3(32, 32),  256, 0, stream>>>(W_a,    WgaT + (size_t)1024 * 1024, 1024, 1024);
  wconv_k<<<dim3(32, 64),  256, 0, stream>>>(W_out,  WoT, 2048, 1024);
  wconv_k<<<dim3(128, 32), 256, 0, stream>>>(W_ff1,  Wf1T, 1024, 4096);
  wconv_k<<<dim3(32, 128), 256, 0, stream>>>(W_ff2,  Wf2T, 4096, 1024);
  // 1. x_norm (bf16)
  rmsnorm_bf_k<<<Mm, 256, 0, stream>>>(x, pre_w, xnbf);
  // 2. conv -> concat[:, 0:D]
  conv_k<<<egrid4, EB, 0, stream>>>(xnbf, conv_w, conv_b, conc);
  // 3. fused gate_pre|a_pre GEMM (N=2048, bf16 out)
  bgemm2_k<8><<<dim3(16, 32), 512, 0, stream>>>(xnbf, WgaT, gapre, Mm, 2048, 1024,
      nullptr, nullptr, nullptr, nullptr, nullptr, nullptr);
  // 4-5. chunked scan (gating fused into P1) -> concat[:, D:2D]
  scan_p1<<<512, 256, 0, stream>>>(gapre, xnbf, lam, ubf, carA, carH);
  scan_p2<<<16, 256, 0, stream>>>(carA, carH, initb);
  scan_p3<<<512, 256, 0, stream>>>(gapre, ubf, lam, initb, conc);
  // 6. mixer GEMM + fused velocity/x_new epilogue: mixer=x_new, out1=velocity
  bgemm2_k<1 | 16><<<dim3(8, 32), 512, 0, stream>>>(conc, WoT, mixer, Mm, 1024, 2048,
      b_out, nullptr, velocity, x, log_beta, out1);
  // 8. normed = rmsnorm(x_new) (bf16)
  rmsnorm_bf_k<<<Mm, 256, 0, stream>>>(mixer, ffn_w, nrmbf);
  // 9. mid = gelu(normed @ W_ff1 + b_ff1) (bf16)
  bgemm2_k<1 | 2 | 8><<<dim3(32, 32), 512, 0, stream>>>(nrmbf, Wf1T, midbf, Mm, 4096, 1024,
      b_ff1, nullptr, nullptr, nullptr, nullptr, nullptr);
  // 10. out0 = mid @ W_ff2 + b_ff2 + x_new (fp32)
  bgemm2_k<1 | 4><<<dim3(8, 32), 512, 0, stream>>>(midbf, Wf2T, out0, Mm, 1024, 4096,
      b_ff2, mixer, nullptr, nullptr, nullptr, nullptr);
}

// Round 2
// 702.163 us; speedup vs baseline: 1.0126x; 1.0126x over previous
//
#include <hip/hip_runtime.h>

// (B,S,D,K,F) = (4, 2048, 1024, 4, 4096)
static constexpr int Bb = 4;
static constexpr int Ss = 2048;
static constexpr int Dd = 1024;
static constexpr int Ff = 4096;
static constexpr int Mm = Bb * Ss;              // 8192 rows
static constexpr size_t ND = (size_t)Mm * Dd;   // 8388608
static constexpr int CH = 32;                   // scan chunks
static constexpr int CL = Ss / CH;              // chunk length 64

typedef __attribute__((ext_vector_type(8))) short short8;
typedef __attribute__((ext_vector_type(4))) float floatx4;

__device__ __forceinline__ unsigned f2bf(float f) {
  unsigned u = __builtin_bit_cast(unsigned, f);
  return (u + 0x7FFFu + ((u >> 16) & 1u)) >> 16;   // RNE
}
__device__ __forceinline__ float bf2f(unsigned bits) {
  return __builtin_bit_cast(float, bits << 16);
}
__device__ __forceinline__ void gload_lds16(const void* g, void* lds) {
  __builtin_amdgcn_global_load_lds((const __attribute__((address_space(1))) void*)g,
                                   (__attribute__((address_space(3))) void*)lds,
                                   16, 0, 0);
}
// fast sigmoid / tanh-gelu via hw v_exp_f32 + v_rcp_f32 (f32-accurate ~1e-6)
__device__ __forceinline__ float fsig(float x) {
  return __builtin_amdgcn_rcpf(1.0f + __expf(-x));
}
__device__ __forceinline__ float fgelu(float v) {
  float z = 1.5957691216057308f * fmaf(0.044715f * v, v * v, v);
  return v * __builtin_amdgcn_rcpf(1.0f + __expf(-z));
}

// ---------------- weight transpose + fp32->bf16: W[K][N] -> WT[N][K] --------
__global__ __launch_bounds__(256) void wconv_k(const float* __restrict__ W,
                                               unsigned short* __restrict__ WT,
                                               int K, int N) {
  __shared__ float tile[32][33];
  int tx = threadIdx.x & 31, ty = threadIdx.x >> 5;
  int bx = blockIdx.x * 32, by = blockIdx.y * 32;
#pragma unroll
  for (int i = 0; i < 32; i += 8)
    tile[ty + i][tx] = W[(size_t)(by + ty + i) * N + bx + tx];
  __syncthreads();
#pragma unroll
  for (int i = 0; i < 32; i += 8)
    WT[(size_t)(bx + ty + i) * K + by + tx] = (unsigned short)f2bf(tile[tx][ty + i]);
}

// ---------------- RMSNorm: fp32 in, bf16 out --------------------------------
__global__ __launch_bounds__(256) void rmsnorm_bf_k(const float* __restrict__ x,
                                                    const float* __restrict__ w,
                                                    unsigned short* __restrict__ out) {
  int row = blockIdx.x;
  const float4* xr = (const float4*)(x + (size_t)row * Dd);
  int t = threadIdx.x;
  float4 v = xr[t];
  float ss = v.x * v.x + v.y * v.y + v.z * v.z + v.w * v.w;
#pragma unroll
  for (int off = 32; off > 0; off >>= 1) ss += __shfl_down(ss, off, 64);
  __shared__ float sb[4];
  if ((t & 63) == 0) sb[t >> 6] = ss;
  __syncthreads();
  float tot = sb[0] + sb[1] + sb[2] + sb[3];
  float sc = rsqrtf(tot * (1.0f / (float)Dd) + 1e-6f);
  float4 wv = ((const float4*)w)[t];
  unsigned lo = f2bf(v.x * sc * wv.x) | (f2bf(v.y * sc * wv.y) << 16);
  unsigned hi = f2bf(v.z * sc * wv.z) | (f2bf(v.w * sc * wv.w) << 16);
  *(uint2*)(out + (size_t)row * Dd + t * 4) = make_uint2(lo, hi);
}

// ---------------- Causal depthwise conv (bf16 in/out) -> concat[:,0:D] ------
__global__ __launch_bounds__(256) void conv_k(const unsigned short* __restrict__ xn,
                                              const float* __restrict__ kern,
                                              const float* __restrict__ bias,
                                              unsigned short* __restrict__ outC) {
  size_t q = (size_t)blockIdx.x * 256 + threadIdx.x;  // over ND/4
  size_t i = q * 4;
  int d = (int)(i & (Dd - 1));
  int m = (int)(i >> 10);
  int t = m & (Ss - 1);
  float acc[4];
#pragma unroll
  for (int j = 0; j < 4; j++) acc[j] = bias[d + j];
#pragma unroll
  for (int k = 0; k < 4; k++) {
    if (t >= k) {
      uint2 xv = *(const uint2*)(xn + i - (size_t)k * Dd);
      float x0 = bf2f(xv.x & 0xFFFF), x1 = bf2f(xv.x >> 16);
      float x2 = bf2f(xv.y & 0xFFFF), x3 = bf2f(xv.y >> 16);
      acc[0] = fmaf(kern[(d + 0) * 4 + k], x0, acc[0]);
      acc[1] = fmaf(kern[(d + 1) * 4 + k], x1, acc[1]);
      acc[2] = fmaf(kern[(d + 2) * 4 + k], x2, acc[2]);
      acc[3] = fmaf(kern[(d + 3) * 4 + k], x3, acc[3]);
    }
  }
  unsigned lo = f2bf(acc[0]) | (f2bf(acc[1]) << 16);
  unsigned hi = f2bf(acc[2]) | (f2bf(acc[3]) << 16);
  *(uint2*)(outC + (size_t)m * (2 * Dd) + d) = make_uint2(lo, hi);
}

// ---------------- bf16 MFMA GEMM v3: C[M,N] = A[M,K] @ BT[N,K]^T ------------
// BM=256, BN=128, BK=64. 512 threads = 8 waves (4M x 2N), per-wave 64x64.
// v3 changes vs v2 (which regressed: FETCH 276MB on gate|a = 14x A over-fetch
// from default x-fastest XCD round-robin; MfmaUtil 17%):
//  * chunked bijective XCD swizzle: each XCD owns a contiguous row-chunk of
//    the grid -> A panel fetched once per XCD-chunk, B re-reads hit L3.
//    (requires nwg%8==0 -- true for all four GEMM shapes here)
//  * 2 phases/K-tile (16 MFMA per barrier cluster) instead of 4 (8 MFMA).
// Kept: triple-buffer LDS ring + counted vmcnt(6) at tile boundaries (T4),
// setprio around MFMA (T5), 16B-block XOR LDS swizzle (T2; SQ_LDS_BANK_
// CONFLICT measured 0 in v2 -- verified working).
// MODE bits: 1=+bias[col], 2=gelu, 4=+extra (fp32), 8=bf16 out, 16=velocity
template <int MODE>
__global__ __launch_bounds__(512, 2) void bgemm2_k(const unsigned short* __restrict__ A,
                                                   const unsigned short* __restrict__ BT,
                                                   void* __restrict__ Cout,
                                                   int M, int N, int K,
                                                   const float* __restrict__ bias,
                                                   const float* __restrict__ extra,
                                                   const float* __restrict__ vel_in,
                                                   const float* __restrict__ x_in,
                                                   const float* __restrict__ log_beta,
                                                   float* __restrict__ vel_out) {
  __shared__ unsigned short As[3][256 * 64];   // 96 KiB
  __shared__ unsigned short Bs[3][128 * 64];   // 48 KiB
  const int tid = threadIdx.x;
  const int wid = tid >> 6, lane = tid & 63;
  const int wm = wid >> 1, wn = wid & 1;       // 4M x 2N wave grid
  const int r = lane & 15, quad = lane >> 4, r7 = lane & 7;

  // ---- chunked XCD swizzle: hw blocks with id%8==k -> XCD k; give XCD k the
  // contiguous work chunk [k*cpx, (k+1)*cpx) (x-fastest => row-major chunks).
  const int gx = gridDim.x;
  int id = blockIdx.y * gx + blockIdx.x;
  const int nwg = gx * gridDim.y;              // divisible by 8 for all shapes
  id = (id & 7) * (nwg >> 3) + (id >> 3);
  const int bm = (id / gx) * 256, bn = (id % gx) * 128;
  const int NT = K >> 6;                        // K-tiles of 64 (>= 16 here)

  // ---- staging geometry: 1 KiB wave-chunks = 8 rows x 128B; A 32 chunks
  // (wave w -> chunks w*4+c), B 16 chunks (w*2+c). Per-lane source block is
  // pre-swizzled so that linear LDS placement == swizzled layout.
  const int lrow = lane >> 3;                  // row within 8-row chunk
  const int sblk = (lane & 7) ^ lrow;          // pre-swizzled 16B block index
  const unsigned short* Asrc = A  + (size_t)(bm + wid * 32 + lrow) * K + sblk * 8;
  const unsigned short* Bsrc = BT + (size_t)(bn + wid * 16 + lrow) * K + sblk * 8;

  // ---- fragment-read addressing (element offsets, swizzled k-block)
  const int aBase = (wm * 64 + r) * 64;
  const int bBase = (wn * 64 + r) * 64;
  const int kq0 = ((quad) ^ r7) * 8;           // ks=0 : blocks 0..3 ^ row&7
  const int kq1 = ((4 + quad) ^ r7) * 8;       // ks=1 : blocks 4..7 ^ row&7

  floatx4 acc[4][4];
#pragma unroll
  for (int i = 0; i < 4; i++)
#pragma unroll
    for (int j = 0; j < 4; j++) acc[i][j] = (floatx4){0.f, 0.f, 0.f, 0.f};

#define STG_A(bq, k0, c) gload_lds16(Asrc + (size_t)(c) * 8 * K + (k0), (void*)&As[bq][(wid * 4 + (c)) * 512])
#define STG_B(bq, k0, c) gload_lds16(Bsrc + (size_t)(c) * 8 * K + (k0), (void*)&Bs[bq][(wid * 2 + (c)) * 512])
#define LD_A(i, ks) aF[i][ks] = *(const short8*)&Ab[aBase + (i) * 1024 + ((ks) ? kq1 : kq0)]
#define LD_B(j, ks) bF[j][ks] = *(const short8*)&Bbuf[bBase + (j) * 1024 + ((ks) ? kq1 : kq0)]
#define MFMA4(i, j)                                                                         \
  acc[i][j] = __builtin_amdgcn_mfma_f32_16x16x32_bf16(bF[j][0], aF[i][0], acc[i][j], 0, 0, 0); \
  acc[i][j] = __builtin_amdgcn_mfma_f32_16x16x32_bf16(bF[j][1], aF[i][1], acc[i][j], 0, 0, 0)

  // ---- prologue: stage tiles 0 and 1 (12 loads/thread), wait for tile 0
  STG_A(0, 0, 0); STG_A(0, 0, 1); STG_A(0, 0, 2); STG_A(0, 0, 3);
  STG_B(0, 0, 0); STG_B(0, 0, 1);
  STG_A(1, 64, 0); STG_A(1, 64, 1); STG_A(1, 64, 2); STG_A(1, 64, 3);
  STG_B(1, 64, 0); STG_B(1, 64, 1);
  asm volatile("s_waitcnt vmcnt(6)" ::: "memory");
  __builtin_amdgcn_s_barrier();
  asm volatile("" ::: "memory");
  __builtin_amdgcn_sched_barrier(0);

  for (int t = 0; t < NT; ++t) {
    const unsigned short* Ab = &As[t % 3][0];
    const unsigned short* Bbuf = &Bs[t % 3][0];
    const int pf = (t + 2 < NT);                // prefetch tile t+2 exists
    const int pbuf = (t + 2) % 3;
    const int pk0 = (t + 2) * 64;
    short8 aF[4][2], bF[4][2];

    // -- phase 0: stage A c0..c2; read aF[01] + all bF; MFMA (i01 x j0123)
    if (pf) { STG_A(pbuf, pk0, 0); STG_A(pbuf, pk0, 1); STG_A(pbuf, pk0, 2); }
    LD_A(0, 0); LD_A(0, 1); LD_A(1, 0); LD_A(1, 1);
    LD_B(0, 0); LD_B(0, 1); LD_B(1, 0); LD_B(1, 1);
    LD_B(2, 0); LD_B(2, 1); LD_B(3, 0); LD_B(3, 1);
    __builtin_amdgcn_s_barrier();
    __builtin_amdgcn_s_setprio(1);
    MFMA4(0, 0); MFMA4(0, 1); MFMA4(0, 2); MFMA4(0, 3);
    MFMA4(1, 0); MFMA4(1, 1); MFMA4(1, 2); MFMA4(1, 3);
    __builtin_amdgcn_s_setprio(0);
    __builtin_amdgcn_s_barrier();

    // -- phase 1: stage A c3 + B c0,c1; read aF[23]; MFMA (i23 x j0123)
    if (pf) { STG_A(pbuf, pk0, 3); STG_B(pbuf, pk0, 0); STG_B(pbuf, pk0, 1); }
    LD_A(2, 0); LD_A(2, 1); LD_A(3, 0); LD_A(3, 1);
    __builtin_amdgcn_s_barrier();
    __builtin_amdgcn_s_setprio(1);
    MFMA4(2, 0); MFMA4(2, 1); MFMA4(2, 2); MFMA4(2, 3);
    MFMA4(3, 0); MFMA4(3, 1); MFMA4(3, 2); MFMA4(3, 3);
    __builtin_amdgcn_s_setprio(0);

    // -- tile boundary: counted wait for tile t+1's staging, then converge.
    if (t + 1 < NT) {
      if (pf) asm volatile("s_waitcnt vmcnt(6)" ::: "memory");
      else    asm volatile("s_waitcnt vmcnt(0)" ::: "memory");
      __builtin_amdgcn_s_barrier();
      asm volatile("" ::: "memory");
      __builtin_amdgcn_sched_barrier(0);
    }
  }
#undef STG_A
#undef STG_B
#undef LD_A
#undef LD_B
#undef MFMA4

  // acc[i][j][0..3] = C[row = bm+wm*64+i*16+r][col = bn+wn*64+j*16+quad*4 +0..3]
#pragma unroll
  for (int i = 0; i < 4; i++) {
    int rowg = bm + wm * 64 + i * 16 + r;
#pragma unroll
    for (int j = 0; j < 4; j++) {
      int colg = bn + wn * 64 + j * 16 + quad * 4;
      size_t idx = (size_t)rowg * N + colg;
      float v0 = acc[i][j][0], v1 = acc[i][j][1], v2 = acc[i][j][2], v3 = acc[i][j][3];
      if (MODE & 1) {
        float4 bv = *(const float4*)(bias + colg);
        v0 += bv.x; v1 += bv.y; v2 += bv.z; v3 += bv.w;
      }
      if (MODE & 2) {
        v0 = fgelu(v0); v1 = fgelu(v1); v2 = fgelu(v2); v3 = fgelu(v3);
      }
      if (MODE & 4) {
        float4 ev = *(const float4*)(extra + idx);
        v0 += ev.x; v1 += ev.y; v2 += ev.z; v3 += ev.w;
      }
      if (MODE & 16) {
        float4 lb = *(const float4*)(log_beta + colg);
        float4 vi = *(const float4*)(vel_in + idx);
        float4 xi = *(const float4*)(x_in + idx);
        float4 vn;
        vn.x = fmaf(fsig(lb.x), vi.x, v0);
        vn.y = fmaf(fsig(lb.y), vi.y, v1);
        vn.z = fmaf(fsig(lb.z), vi.z, v2);
        vn.w = fmaf(fsig(lb.w), vi.w, v3);
        *(float4*)(vel_out + idx) = vn;
        v0 = xi.x + vn.x; v1 = xi.y + vn.y; v2 = xi.z + vn.z; v3 = xi.w + vn.w;
      }
      if (MODE & 8) {
        uint2 pk;
        pk.x = f2bf(v0) | (f2bf(v1) << 16);
        pk.y = f2bf(v2) | (f2bf(v3) << 16);
        *(uint2*)((unsigned short*)Cout + idx) = pk;
      } else {
        float4 o; o.x = v0; o.y = v1; o.z = v2; o.w = v3;
        *(float4*)((float*)Cout + idx) = o;
      }
    }
  }
}

// ---------------- scan phase 1: gating + per-chunk (A, h_local) -------------
__global__ __launch_bounds__(256) void scan_p1(const unsigned short* __restrict__ gapre,
                                               const unsigned short* __restrict__ xn,
                                               const float* __restrict__ lam,
                                               unsigned short* __restrict__ ub,
                                               float* __restrict__ carryA,
                                               float* __restrict__ carryH) {
  int g = blockIdx.x * 256 + threadIdx.x;    // 0..131071
  int e = g & (Dd - 1);
  int bc = g >> 10;
  int b = bc & 3;
  int c = bc >> 2;
  float l = lam[e];
  float sp = fmaxf(l, 0.0f) + log1pf(__expf(-fabsf(l)));
  float m8sp = -8.0f * sp;
  size_t m0 = (size_t)b * Ss + (size_t)c * CL;
  float A = 1.0f, h = 0.0f;
#pragma unroll 4
  for (int t = 0; t < CL; t++) {
    size_t m = m0 + t;
    float gp = bf2f(gapre[m * 2048 + e]);
    float ap = bf2f(gapre[m * 2048 + 1024 + e]);
    float xv = bf2f(xn[m * Dd + e]);
    float a = __expf(m8sp * fsig(ap));
    float u = sqrtf(fmaxf(1.0f - a * a, 0.0f)) * fsig(gp) * xv;
    ub[m * Dd + e] = (unsigned short)f2bf(u);
    A *= a;
    h = fmaf(a, h, u);
  }
  carryA[c * 4096 + b * 1024 + e] = A;
  carryH[c * 4096 + b * 1024 + e] = h;
}

// ---------------- scan phase 2: scan carries -> per-chunk init state --------
__global__ __launch_bounds__(256) void scan_p2(const float* __restrict__ carryA,
                                               const float* __restrict__ carryH,
                                               float* __restrict__ init) {
  int ch = blockIdx.x * 256 + threadIdx.x;   // 0..4095
  float H = 0.0f;
#pragma unroll
  for (int c = 0; c < CH; c++) {
    init[c * 4096 + ch] = H;
    H = fmaf(carryA[c * 4096 + ch], H, carryH[c * 4096 + ch]);
  }
}

// ---------------- scan phase 3: rescan chunk with init -> concat[:,D:2D] ----
__global__ __launch_bounds__(256) void scan_p3(const unsigned short* __restrict__ gapre,
                                               const unsigned short* __restrict__ ub,
                                               const float* __restrict__ lam,
                                               const float* __restrict__ init,
                                               unsigned short* __restrict__ outC) {
  int g = blockIdx.x * 256 + threadIdx.x;
  int e = g & (Dd - 1);
  int bc = g >> 10;
  int b = bc & 3;
  int c = bc >> 2;
  float l = lam[e];
  float sp = fmaxf(l, 0.0f) + log1pf(__expf(-fabsf(l)));
  float m8sp = -8.0f * sp;
  size_t m0 = (size_t)b * Ss + (size_t)c * CL;
  float h = init[c * 4096 + b * 1024 + e];
#pragma unroll 4
  for (int t = 0; t < CL; t++) {
    size_t m = m0 + t;
    float ap = bf2f(gapre[m * 2048 + 1024 + e]);
    float a = __expf(m8sp * fsig(ap));
    float u = bf2f(ub[m * Dd + e]);
    h = fmaf(a, h, u);
    outC[m * (2 * Dd) + Dd + e] = (unsigned short)f2bf(h);
  }
}

extern "C" void kernel_launch(void* const* d_in, const int* in_sizes, int n_in,
                              void* d_out, int out_size, void* d_ws, size_t ws_size,
                              hipStream_t stream) {
  const float* x        = (const float*)d_in[0];
  const float* velocity = (const float*)d_in[1];
  const float* pre_w    = (const float*)d_in[2];
  const float* conv_w   = (const float*)d_in[3];
  const float* conv_b   = (const float*)d_in[4];
  const float* W_gate   = (const float*)d_in[5];
  const float* W_a      = (const float*)d_in[6];
  const float* lam      = (const float*)d_in[7];
  const float* W_out    = (const float*)d_in[8];
  const float* b_out    = (const float*)d_in[9];
  const float* log_beta = (const float*)d_in[10];
  const float* ffn_w    = (const float*)d_in[11];
  const float* W_ff1    = (const float*)d_in[12];
  const float* b_ff1    = (const float*)d_in[13];
  const float* W_ff2    = (const float*)d_in[14];
  const float* b_ff2    = (const float*)d_in[15];

  float* out0 = (float*)d_out;
  float* out1 = out0 + ND;

  // ---- workspace (byte offsets), lifetime-aliased; peak 152 MB ----
  const size_t MB = 1024 * 1024;
  char* ws = (char*)d_ws;
  unsigned short* WgaT  = (unsigned short*)ws;               // 2048x1024 [0,4) (gate|a)
  unsigned short* WoT   = WgaT + (size_t)2 * 1024 * 1024;    // [4,8)
  unsigned short* Wf1T  = WoT + (size_t)2 * 1024 * 1024;     // [8,16)
  unsigned short* Wf2T  = Wf1T + (size_t)4 * 1024 * 1024;    // [16,24)
  float*          mixer = (float*)(ws + 24 * MB);            // 32 MB [24,56) — x_new
  float*          carA  = (float*)(ws + 24 * MB);            // overlay (pre-step-6)
  float*          carH  = (float*)(ws + 24 * MB + 512 * 1024);
  float*          initb = (float*)(ws + 25 * MB);
  unsigned short* conc  = (unsigned short*)(ws + 56 * MB);   // 32 MB [56,88)
  unsigned short* gapre = (unsigned short*)(ws + 88 * MB);   // 32 MB [88,120)
  unsigned short* xnbf  = (unsigned short*)(ws + 120 * MB);  // 16 MB [120,136)
  unsigned short* ubf   = (unsigned short*)(ws + 136 * MB);  // 16 MB [136,152)
  unsigned short* midbf = (unsigned short*)(ws + 88 * MB);   // 64 MB overlay [88,152)
  unsigned short* nrmbf = (unsigned short*)(ws + 56 * MB);   // overlay conc

  const int EB = 256;
  const int egrid4 = (int)(ND / 4 / EB);

  // 0. weight transpose + bf16 convert (gate|a combined, contiguous)
  wconv_k<<<dim3(32, 32),  256, 0, stream>>>(W_gate, WgaT, 1024, 1024);
  wconv_k<<<dim3(32, 32),  256, 0, stream>>>(W_a,    WgaT + (size_t)1024 * 1024, 1024, 1024);
  wconv_k<<<dim3(32, 64),  256, 0, stream>>>(W_out,  WoT, 2048, 1024);
  wconv_k<<<dim3(128, 32), 256, 0, stream>>>(W_ff1,  Wf1T, 1024, 4096);
  wconv_k<<<dim3(32, 128), 256, 0, stream>>>(W_ff2,  Wf2T, 4096, 1024);
  // 1. x_norm (bf16)
  rmsnorm_bf_k<<<Mm, 256, 0, stream>>>(x, pre_w, xnbf);
  // 2. conv -> concat[:, 0:D]
  conv_k<<<egrid4, EB, 0, stream>>>(xnbf, conv_w, conv_b, conc);
  // 3. fused gate_pre|a_pre GEMM (N=2048, bf16 out)
  bgemm2_k<8><<<dim3(16, 32), 512, 0, stream>>>(xnbf, WgaT, gapre, Mm, 2048, 1024,
      nullptr, nullptr, nullptr, nullptr, nullptr, nullptr);
  // 4-5. chunked scan (gating fused into P1) -> concat[:, D:2D]
  scan_p1<<<512, 256, 0, stream>>>(gapre, xnbf, lam, ubf, carA, carH);
  scan_p2<<<16, 256, 0, stream>>>(carA, carH, initb);
  scan_p3<<<512, 256, 0, stream>>>(gapre, ubf, lam, initb, conc);
  // 6. mixer GEMM + fused velocity/x_new epilogue: mixer=x_new, out1=velocity
  bgemm2_k<1 | 16><<<dim3(8, 32), 512, 0, stream>>>(conc, WoT, mixer, Mm, 1024, 2048,
      b_out, nullptr, velocity, x, log_beta, out1);
  // 8. normed = rmsnorm(x_new) (bf16)
  rmsnorm_bf_k<<<Mm, 256, 0, stream>>>(mixer, ffn_w, nrmbf);
  // 9. mid = gelu(normed @ W_ff1 + b_ff1) (bf16)
  bgemm2_k<1 | 2 | 8><<<dim3(32, 32), 512, 0, stream>>>(nrmbf, Wf1T, midbf, Mm, 4096, 1024,
      b_ff1, nullptr, nullptr, nullptr, nullptr, nullptr);
  // 10. out0 = mid @ W_ff2 + b_ff2 + x_new (fp32)
  bgemm2_k<1 | 4><<<dim3(8, 32), 512, 0, stream>>>(midbf, Wf2T, out0, Mm, 1024, 4096,
      b_ff2, mixer, nullptr, nullptr, nullptr, nullptr);
}

// Round 4
// 653.317 us; speedup vs baseline: 1.0884x; 1.0748x over previous
//
#include <hip/hip_runtime.h>

// (B,S,D,K,F) = (4, 2048, 1024, 4, 4096)
static constexpr int Bb = 4;
static constexpr int Ss = 2048;
static constexpr int Dd = 1024;
static constexpr int Ff = 4096;
static constexpr int Mm = Bb * Ss;              // 8192 rows
static constexpr size_t ND = (size_t)Mm * Dd;   // 8388608
static constexpr int CH = 32;                   // scan chunks
static constexpr int CL = Ss / CH;              // chunk length 64

typedef __attribute__((ext_vector_type(8))) short short8;
typedef __attribute__((ext_vector_type(4))) float floatx4;

__device__ __forceinline__ unsigned f2bf(float f) {
  unsigned u = __builtin_bit_cast(unsigned, f);
  return (u + 0x7FFFu + ((u >> 16) & 1u)) >> 16;   // RNE
}
__device__ __forceinline__ float bf2f(unsigned bits) {
  return __builtin_bit_cast(float, bits << 16);
}
__device__ __forceinline__ void gload_lds16(const void* g, void* lds) {
  __builtin_amdgcn_global_load_lds((const __attribute__((address_space(1))) void*)g,
                                   (__attribute__((address_space(3))) void*)lds,
                                   16, 0, 0);
}
// fast sigmoid / tanh-gelu via hw v_exp_f32 + v_rcp_f32 (f32-accurate ~1e-6)
__device__ __forceinline__ float fsig(float x) {
  return __builtin_amdgcn_rcpf(1.0f + __expf(-x));
}
__device__ __forceinline__ float fgelu(float v) {
  float z = 1.5957691216057308f * fmaf(0.044715f * v, v * v, v);
  return v * __builtin_amdgcn_rcpf(1.0f + __expf(-z));
}

// ---------------- weight transpose + fp32->bf16: W[K][N] -> WT[N][K] --------
__global__ __launch_bounds__(256) void wconv_k(const float* __restrict__ W,
                                               unsigned short* __restrict__ WT,
                                               int K, int N) {
  __shared__ float tile[32][33];
  int tx = threadIdx.x & 31, ty = threadIdx.x >> 5;
  int bx = blockIdx.x * 32, by = blockIdx.y * 32;
#pragma unroll
  for (int i = 0; i < 32; i += 8)
    tile[ty + i][tx] = W[(size_t)(by + ty + i) * N + bx + tx];
  __syncthreads();
#pragma unroll
  for (int i = 0; i < 32; i += 8)
    WT[(size_t)(bx + ty + i) * K + by + tx] = (unsigned short)f2bf(tile[tx][ty + i]);
}

// ---------------- RMSNorm: fp32 in, bf16 out --------------------------------
__global__ __launch_bounds__(256) void rmsnorm_bf_k(const float* __restrict__ x,
                                                    const float* __restrict__ w,
                                                    unsigned short* __restrict__ out) {
  int row = blockIdx.x;
  const float4* xr = (const float4*)(x + (size_t)row * Dd);
  int t = threadIdx.x;
  float4 v = xr[t];
  float ss = v.x * v.x + v.y * v.y + v.z * v.z + v.w * v.w;
#pragma unroll
  for (int off = 32; off > 0; off >>= 1) ss += __shfl_down(ss, off, 64);
  __shared__ float sb[4];
  if ((t & 63) == 0) sb[t >> 6] = ss;
  __syncthreads();
  float tot = sb[0] + sb[1] + sb[2] + sb[3];
  float sc = rsqrtf(tot * (1.0f / (float)Dd) + 1e-6f);
  float4 wv = ((const float4*)w)[t];
  unsigned lo = f2bf(v.x * sc * wv.x) | (f2bf(v.y * sc * wv.y) << 16);
  unsigned hi = f2bf(v.z * sc * wv.z) | (f2bf(v.w * sc * wv.w) << 16);
  *(uint2*)(out + (size_t)row * Dd + t * 4) = make_uint2(lo, hi);
}

// ---------------- Causal depthwise conv (bf16 in/out) -> concat[:,0:D] ------
__global__ __launch_bounds__(256) void conv_k(const unsigned short* __restrict__ xn,
                                              const float* __restrict__ kern,
                                              const float* __restrict__ bias,
                                              unsigned short* __restrict__ outC) {
  size_t q = (size_t)blockIdx.x * 256 + threadIdx.x;  // over ND/4
  size_t i = q * 4;
  int d = (int)(i & (Dd - 1));
  int m = (int)(i >> 10);
  int t = m & (Ss - 1);
  float acc[4];
#pragma unroll
  for (int j = 0; j < 4; j++) acc[j] = bias[d + j];
#pragma unroll
  for (int k = 0; k < 4; k++) {
    if (t >= k) {
      uint2 xv = *(const uint2*)(xn + i - (size_t)k * Dd);
      float x0 = bf2f(xv.x & 0xFFFF), x1 = bf2f(xv.x >> 16);
      float x2 = bf2f(xv.y & 0xFFFF), x3 = bf2f(xv.y >> 16);
      acc[0] = fmaf(kern[(d + 0) * 4 + k], x0, acc[0]);
      acc[1] = fmaf(kern[(d + 1) * 4 + k], x1, acc[1]);
      acc[2] = fmaf(kern[(d + 2) * 4 + k], x2, acc[2]);
      acc[3] = fmaf(kern[(d + 3) * 4 + k], x3, acc[3]);
    }
  }
  unsigned lo = f2bf(acc[0]) | (f2bf(acc[1]) << 16);
  unsigned hi = f2bf(acc[2]) | (f2bf(acc[3]) << 16);
  *(uint2*)(outC + (size_t)m * (2 * Dd) + d) = make_uint2(lo, hi);
}

// ---------------- bf16 MFMA GEMM v4: m201-style 8-phase 256x256 template ----
// C[M,N] = A[M,K] @ BT[N,K]^T. BM=BN=256, BK=64, 512 thr = 8 waves (2M x 4N),
// wave tile 128x64 (acc[8][4] = 128 VGPR). LDS: 2 buffers x (A 32K + B 32K)
// = 128 KiB; even K-tile -> buf0, odd -> buf1. Loop iteration = 2 K-tiles =
// 8 phases. Per phase: stage ONE half-tile (2 gload_lds/thread) + ds_read
// the quadrant fragments + barrier + lgkmcnt(0) + setprio(1) + 16 MFMA +
// setprio(0) + barrier. Counted gates vmcnt(4) at phases 4 & 8 (FIFO-derived:
// leaves exactly the 2 youngest half-tiles in flight; vmcnt(0) only in the
// final iteration). Stage schedule (race-checked, region free-times derived
// from quadrant read order A:p0/p2, B:p0/p1):
//   p0,p1: A(T+1)->buf1 | p2,p3: B(T+2)->buf0 | p4,p5: A(T+2)->buf0
//   p6,p7: B(T+3)->buf1 ; prologue: tile0(A,B)->buf0, B(1)->buf1, vmcnt(4).
// Kept from verified v3: 16B-block XOR LDS swizzle (measured 0 conflicts),
// pre-swizzled global source, swapped-operand MFMA convention, epilogue,
// chunked bijective XCD swizzle.
// MODE bits: 1=+bias[col], 2=gelu, 4=+extra (fp32), 8=bf16 out, 16=velocity
template <int MODE>
__global__ __launch_bounds__(512, 2) void bgemm3_k(const unsigned short* __restrict__ A,
                                                   const unsigned short* __restrict__ BT,
                                                   void* __restrict__ Cout,
                                                   int M, int N, int K,
                                                   const float* __restrict__ bias,
                                                   const float* __restrict__ extra,
                                                   const float* __restrict__ vel_in,
                                                   const float* __restrict__ x_in,
                                                   const float* __restrict__ log_beta,
                                                   float* __restrict__ vel_out) {
  __shared__ unsigned short LA[2][256 * 64];   // 64 KiB
  __shared__ unsigned short LB[2][256 * 64];   // 64 KiB
  const int tid = threadIdx.x;
  const int wid = tid >> 6, lane = tid & 63;
  const int wm = wid >> 2, wn = wid & 3;       // 2M x 4N wave grid
  const int r = lane & 15, quad = lane >> 4, r7 = lane & 7;

  // ---- chunked XCD swizzle (nwg % 8 == 0 for all four shapes)
  const int gx = gridDim.x;
  int id = blockIdx.y * gx + blockIdx.x;
  const int nwg = gx * gridDim.y;
  id = (id & 7) * (nwg >> 3) + (id >> 3);
  const int bm = (id / gx) * 256, bn = (id % gx) * 256;
  const int NIT = K >> 7;                      // iterations of 2 K-tiles

  // ---- staging: per half-tile (128 rows x 64 K) 2 sweeps of 64 rows; wave w
  // stages rows [.. + w*8, +8). Source block pre-swizzled: sblk = (l&7)^lrow.
  const int lrow = lane >> 3;
  const int sblk = (lane & 7) ^ lrow;
  const unsigned short* AsrcB = A  + (size_t)(bm + lrow) * K + sblk * 8;
  const unsigned short* BsrcB = BT + (size_t)(bn + lrow) * K + sblk * 8;

  // ---- fragment read addressing (element offsets; swizzle uses row&7 == r7)
  const int aB = wm * 8192 + r * 64;
  const int bB = wn * 4096 + r * 64;
  const int kq0 = (quad ^ r7) * 8;
  const int kq1 = ((4 + quad) ^ r7) * 8;

  floatx4 acc[8][4];
#pragma unroll
  for (int i = 0; i < 8; i++)
#pragma unroll
    for (int j = 0; j < 4; j++) acc[i][j] = (floatx4){0.f, 0.f, 0.f, 0.f};

#define STG_A(bq, k0, h, s)                                                           \
  gload_lds16(AsrcB + (size_t)((h) * 128 + (s) * 64 + wid * 8) * K + (k0),            \
              (void*)&LA[bq][((h) * 128 + (s) * 64 + wid * 8) * 64])
#define STG_B(bq, k0, h, s)                                                           \
  gload_lds16(BsrcB + (size_t)((h) * 128 + (s) * 64 + wid * 8) * K + (k0),            \
              (void*)&LB[bq][((h) * 128 + (s) * 64 + wid * 8) * 64])
#define RDA(il, IH, buf)                                                              \
  aF[il][0] = *(const short8*)&LA[buf][aB + (IH) * 4096 + (il) * 1024 + kq0];         \
  aF[il][1] = *(const short8*)&LA[buf][aB + (IH) * 4096 + (il) * 1024 + kq1]
#define RDB(BF, jl, jg, buf)                                                          \
  BF[jl][0] = *(const short8*)&LB[buf][bB + (jg) * 1024 + kq0];                       \
  BF[jl][1] = *(const short8*)&LB[buf][bB + (jg) * 1024 + kq1]
#define MM2(il, jl, BF, IH, JH)                                                       \
  acc[(IH) * 4 + (il)][(JH) * 2 + (jl)] = __builtin_amdgcn_mfma_f32_16x16x32_bf16(    \
      BF[jl][0], aF[il][0], acc[(IH) * 4 + (il)][(JH) * 2 + (jl)], 0, 0, 0);          \
  acc[(IH) * 4 + (il)][(JH) * 2 + (jl)] = __builtin_amdgcn_mfma_f32_16x16x32_bf16(    \
      BF[jl][1], aF[il][1], acc[(IH) * 4 + (il)][(JH) * 2 + (jl)], 0, 0, 0)
#define MQUAD(BF, IH, JH)                                                             \
  MM2(0, 0, BF, IH, JH); MM2(0, 1, BF, IH, JH); MM2(1, 0, BF, IH, JH);                \
  MM2(1, 1, BF, IH, JH); MM2(2, 0, BF, IH, JH); MM2(2, 1, BF, IH, JH);                \
  MM2(3, 0, BF, IH, JH); MM2(3, 1, BF, IH, JH)
#define BAR() __builtin_amdgcn_s_barrier()
#define LGK0()                                                                        \
  asm volatile("s_waitcnt lgkmcnt(0)" ::: "memory");                                  \
  __builtin_amdgcn_sched_barrier(0)
#define PRIO(x) __builtin_amdgcn_s_setprio(x)

  // ---- prologue: tile0 (A+B) -> buf0, tile1 B -> buf1; drain tile0 only.
  STG_A(0, 0, 0, 0); STG_A(0, 0, 0, 1); STG_A(0, 0, 1, 0); STG_A(0, 0, 1, 1);
  STG_B(0, 0, 0, 0); STG_B(0, 0, 0, 1); STG_B(0, 0, 1, 0); STG_B(0, 0, 1, 1);
  STG_B(1, 64, 0, 0); STG_B(1, 64, 0, 1); STG_B(1, 64, 1, 0); STG_B(1, 64, 1, 1);
  asm volatile("s_waitcnt vmcnt(4)" ::: "memory");
  BAR();
  __builtin_amdgcn_sched_barrier(0);

  for (int it = 0; it < NIT; ++it) {
    const int T = 2 * it;
    const int pf = (it + 1 < NIT);
    const int kA1 = (T + 1) << 6;
    const int k2 = (T + 2) << 6, k3 = (T + 3) << 6;
    short8 aF[4][2], b0[2][2], b1[2][2];

    // p0: stage A-h0(T+1)->buf1 ; read A-q0 + B-q0 of T (buf0); MFMA quad(0,0)
    STG_A(1, kA1, 0, 0); STG_A(1, kA1, 0, 1);
    RDA(0, 0, 0); RDA(1, 0, 0); RDA(2, 0, 0); RDA(3, 0, 0);
    RDB(b0, 0, 0, 0); RDB(b0, 1, 1, 0);
    BAR(); LGK0();
    PRIO(1); MQUAD(b0, 0, 0); PRIO(0);
    BAR();

    // p1: stage A-h1(T+1)->buf1 ; read B-q1 of T; MFMA quad(0,1)
    STG_A(1, kA1, 1, 0); STG_A(1, kA1, 1, 1);
    RDB(b1, 0, 2, 0); RDB(b1, 1, 3, 0);
    BAR(); LGK0();
    PRIO(1); MQUAD(b1, 0, 1); PRIO(0);
    BAR();

    // p2: stage B-h0(T+2)->buf0 ; read A-q1 of T; MFMA quad(1,0)
    if (pf) { STG_B(0, k2, 0, 0); STG_B(0, k2, 0, 1); }
    RDA(0, 1, 0); RDA(1, 1, 0); RDA(2, 1, 0); RDA(3, 1, 0);
    BAR(); LGK0();
    PRIO(1); MQUAD(b0, 1, 0); PRIO(0);
    BAR();

    // p3: stage B-h1(T+2)->buf0 ; MFMA quad(1,1) ; GATE 1
    if (pf) { STG_B(0, k2, 1, 0); STG_B(0, k2, 1, 1); }
    BAR();
    PRIO(1); MQUAD(b1, 1, 1); PRIO(0);
    if (pf) asm volatile("s_waitcnt vmcnt(4)" ::: "memory");
    else    asm volatile("s_waitcnt vmcnt(0)" ::: "memory");
    BAR();
    __builtin_amdgcn_sched_barrier(0);

    // p4: stage A-h0(T+2)->buf0 ; read A-q0 + B-q0 of T+1 (buf1); MFMA (0,0)
    if (pf) { STG_A(0, k2, 0, 0); STG_A(0, k2, 0, 1); }
    RDA(0, 0, 1); RDA(1, 0, 1); RDA(2, 0, 1); RDA(3, 0, 1);
    RDB(b0, 0, 0, 1); RDB(b0, 1, 1, 1);
    BAR(); LGK0();
    PRIO(1); MQUAD(b0, 0, 0); PRIO(0);
    BAR();

    // p5: stage A-h1(T+2)->buf0 ; read B-q1 of T+1; MFMA (0,1)
    if (pf) { STG_A(0, k2, 1, 0); STG_A(0, k2, 1, 1); }
    RDB(b1, 0, 2, 1); RDB(b1, 1, 3, 1);
    BAR(); LGK0();
    PRIO(1); MQUAD(b1, 0, 1); PRIO(0);
    BAR();

    // p6: stage B-h0(T+3)->buf1 ; read A-q1 of T+1; MFMA (1,0)
    if (pf) { STG_B(1, k3, 0, 0); STG_B(1, k3, 0, 1); }
    RDA(0, 1, 1); RDA(1, 1, 1); RDA(2, 1, 1); RDA(3, 1, 1);
    BAR(); LGK0();
    PRIO(1); MQUAD(b0, 1, 0); PRIO(0);
    BAR();

    // p7: stage B-h1(T+3)->buf1 ; MFMA (1,1) ; GATE 2 (skipped on final iter)
    if (pf) { STG_B(1, k3, 1, 0); STG_B(1, k3, 1, 1); }
    BAR();
    PRIO(1); MQUAD(b1, 1, 1); PRIO(0);
    if (pf) {
      asm volatile("s_waitcnt vmcnt(4)" ::: "memory");
      BAR();
      __builtin_amdgcn_sched_barrier(0);
    }
  }
#undef STG_A
#undef STG_B
#undef RDA
#undef RDB
#undef MM2
#undef MQUAD
#undef BAR
#undef LGK0
#undef PRIO

  // acc[i][j][0..3] = C[row = bm+wm*128+i*16+r][col = bn+wn*64+j*16+quad*4 +0..3]
#pragma unroll
  for (int i = 0; i < 8; i++) {
    int rowg = bm + wm * 128 + i * 16 + r;
#pragma unroll
    for (int j = 0; j < 4; j++) {
      int colg = bn + wn * 64 + j * 16 + quad * 4;
      size_t idx = (size_t)rowg * N + colg;
      float v0 = acc[i][j][0], v1 = acc[i][j][1], v2 = acc[i][j][2], v3 = acc[i][j][3];
      if (MODE & 1) {
        float4 bv = *(const float4*)(bias + colg);
        v0 += bv.x; v1 += bv.y; v2 += bv.z; v3 += bv.w;
      }
      if (MODE & 2) {
        v0 = fgelu(v0); v1 = fgelu(v1); v2 = fgelu(v2); v3 = fgelu(v3);
      }
      if (MODE & 4) {
        float4 ev = *(const float4*)(extra + idx);
        v0 += ev.x; v1 += ev.y; v2 += ev.z; v3 += ev.w;
      }
      if (MODE & 16) {
        float4 lb = *(const float4*)(log_beta + colg);
        float4 vi = *(const float4*)(vel_in + idx);
        float4 xi = *(const float4*)(x_in + idx);
        float4 vn;
        vn.x = fmaf(fsig(lb.x), vi.x, v0);
        vn.y = fmaf(fsig(lb.y), vi.y, v1);
        vn.z = fmaf(fsig(lb.z), vi.z, v2);
        vn.w = fmaf(fsig(lb.w), vi.w, v3);
        *(float4*)(vel_out + idx) = vn;
        v0 = xi.x + vn.x; v1 = xi.y + vn.y; v2 = xi.z + vn.z; v3 = xi.w + vn.w;
      }
      if (MODE & 8) {
        uint2 pk;
        pk.x = f2bf(v0) | (f2bf(v1) << 16);
        pk.y = f2bf(v2) | (f2bf(v3) << 16);
        *(uint2*)((unsigned short*)Cout + idx) = pk;
      } else {
        float4 o; o.x = v0; o.y = v1; o.z = v2; o.w = v3;
        *(float4*)((float*)Cout + idx) = o;
      }
    }
  }
}

// ---------------- scan phase 1: gating + per-chunk (A, h_local) -------------
__global__ __launch_bounds__(256) void scan_p1(const unsigned short* __restrict__ gapre,
                                               const unsigned short* __restrict__ xn,
                                               const float* __restrict__ lam,
                                               unsigned short* __restrict__ ub,
                                               float* __restrict__ carryA,
                                               float* __restrict__ carryH) {
  int g = blockIdx.x * 256 + threadIdx.x;    // 0..131071
  int e = g & (Dd - 1);
  int bc = g >> 10;
  int b = bc & 3;
  int c = bc >> 2;
  float l = lam[e];
  float sp = fmaxf(l, 0.0f) + log1pf(__expf(-fabsf(l)));
  float m8sp = -8.0f * sp;
  size_t m0 = (size_t)b * Ss + (size_t)c * CL;
  float A = 1.0f, h = 0.0f;
#pragma unroll 4
  for (int t = 0; t < CL; t++) {
    size_t m = m0 + t;
    float gp = bf2f(gapre[m * 2048 + e]);
    float ap = bf2f(gapre[m * 2048 + 1024 + e]);
    float xv = bf2f(xn[m * Dd + e]);
    float a = __expf(m8sp * fsig(ap));
    float u = sqrtf(fmaxf(1.0f - a * a, 0.0f)) * fsig(gp) * xv;
    ub[m * Dd + e] = (unsigned short)f2bf(u);
    A *= a;
    h = fmaf(a, h, u);
  }
  carryA[c * 4096 + b * 1024 + e] = A;
  carryH[c * 4096 + b * 1024 + e] = h;
}

// ---------------- scan phase 2: scan carries -> per-chunk init state --------
__global__ __launch_bounds__(256) void scan_p2(const float* __restrict__ carryA,
                                               const float* __restrict__ carryH,
                                               float* __restrict__ init) {
  int ch = blockIdx.x * 256 + threadIdx.x;   // 0..4095
  float H = 0.0f;
#pragma unroll
  for (int c = 0; c < CH; c++) {
    init[c * 4096 + ch] = H;
    H = fmaf(carryA[c * 4096 + ch], H, carryH[c * 4096 + ch]);
  }
}

// ---------------- scan phase 3: rescan chunk with init -> concat[:,D:2D] ----
__global__ __launch_bounds__(256) void scan_p3(const unsigned short* __restrict__ gapre,
                                               const unsigned short* __restrict__ ub,
                                               const float* __restrict__ lam,
                                               const float* __restrict__ init,
                                               unsigned short* __restrict__ outC) {
  int g = blockIdx.x * 256 + threadIdx.x;
  int e = g & (Dd - 1);
  int bc = g >> 10;
  int b = bc & 3;
  int c = bc >> 2;
  float l = lam[e];
  float sp = fmaxf(l, 0.0f) + log1pf(__expf(-fabsf(l)));
  float m8sp = -8.0f * sp;
  size_t m0 = (size_t)b * Ss + (size_t)c * CL;
  float h = init[c * 4096 + b * 1024 + e];
#pragma unroll 4
  for (int t = 0; t < CL; t++) {
    size_t m = m0 + t;
    float ap = bf2f(gapre[m * 2048 + 1024 + e]);
    float a = __expf(m8sp * fsig(ap));
    float u = bf2f(ub[m * Dd + e]);
    h = fmaf(a, h, u);
    outC[m * (2 * Dd) + Dd + e] = (unsigned short)f2bf(h);
  }
}

extern "C" void kernel_launch(void* const* d_in, const int* in_sizes, int n_in,
                              void* d_out, int out_size, void* d_ws, size_t ws_size,
                              hipStream_t stream) {
  const float* x        = (const float*)d_in[0];
  const float* velocity = (const float*)d_in[1];
  const float* pre_w    = (const float*)d_in[2];
  const float* conv_w   = (const float*)d_in[3];
  const float* conv_b   = (const float*)d_in[4];
  const float* W_gate   = (const float*)d_in[5];
  const float* W_a      = (const float*)d_in[6];
  const float* lam      = (const float*)d_in[7];
  const float* W_out    = (const float*)d_in[8];
  const float* b_out    = (const float*)d_in[9];
  const float* log_beta = (const float*)d_in[10];
  const float* ffn_w    = (const float*)d_in[11];
  const float* W_ff1    = (const float*)d_in[12];
  const float* b_ff1    = (const float*)d_in[13];
  const float* W_ff2    = (const float*)d_in[14];
  const float* b_ff2    = (const float*)d_in[15];

  float* out0 = (float*)d_out;
  float* out1 = out0 + ND;

  // ---- workspace (byte offsets), lifetime-aliased; peak 152 MB ----
  const size_t MB = 1024 * 1024;
  char* ws = (char*)d_ws;
  unsigned short* WgaT  = (unsigned short*)ws;               // 2048x1024 [0,4) (gate|a)
  unsigned short* WoT   = WgaT + (size_t)2 * 1024 * 1024;    // [4,8)
  unsigned short* Wf1T  = WoT + (size_t)2 * 1024 * 1024;     // [8,16)
  unsigned short* Wf2T  = Wf1T + (size_t)4 * 1024 * 1024;    // [16,24)
  float*          mixer = (float*)(ws + 24 * MB);            // 32 MB [24,56) — x_new
  float*          carA  = (float*)(ws + 24 * MB);            // overlay (pre-step-6)
  float*          carH  = (float*)(ws + 24 * MB + 512 * 1024);
  float*          initb = (float*)(ws + 25 * MB);
  unsigned short* conc  = (unsigned short*)(ws + 56 * MB);   // 32 MB [56,88)
  unsigned short* gapre = (unsigned short*)(ws + 88 * MB);   // 32 MB [88,120)
  unsigned short* xnbf  = (unsigned short*)(ws + 120 * MB);  // 16 MB [120,136)
  unsigned short* ubf   = (unsigned short*)(ws + 136 * MB);  // 16 MB [136,152)
  unsigned short* midbf = (unsigned short*)(ws + 88 * MB);   // 64 MB overlay [88,152)
  unsigned short* nrmbf = (unsigned short*)(ws + 56 * MB);   // overlay conc

  const int EB = 256;
  const int egrid4 = (int)(ND / 4 / EB);

  // 0. weight transpose + bf16 convert (gate|a combined, contiguous)
  wconv_k<<<dim3(32, 32),  256, 0, stream>>>(W_gate, WgaT, 1024, 1024);
  wconv_k<<<dim3(32, 32),  256, 0, stream>>>(W_a,    WgaT + (size_t)1024 * 1024, 1024, 1024);
  wconv_k<<<dim3(32, 64),  256, 0, stream>>>(W_out,  WoT, 2048, 1024);
  wconv_k<<<dim3(128, 32), 256, 0, stream>>>(W_ff1,  Wf1T, 1024, 4096);
  wconv_k<<<dim3(32, 128), 256, 0, stream>>>(W_ff2,  Wf2T, 4096, 1024);
  // 1. x_norm (bf16)
  rmsnorm_bf_k<<<Mm, 256, 0, stream>>>(x, pre_w, xnbf);
  // 2. conv -> concat[:, 0:D]
  conv_k<<<egrid4, EB, 0, stream>>>(xnbf, conv_w, conv_b, conc);
  // 3. fused gate_pre|a_pre GEMM (N=2048, bf16 out)
  bgemm3_k<8><<<dim3(8, 32), 512, 0, stream>>>(xnbf, WgaT, gapre, Mm, 2048, 1024,
      nullptr, nullptr, nullptr, nullptr, nullptr, nullptr);
  // 4-5. chunked scan (gating fused into P1) -> concat[:, D:2D]
  scan_p1<<<512, 256, 0, stream>>>(gapre, xnbf, lam, ubf, carA, carH);
  scan_p2<<<16, 256, 0, stream>>>(carA, carH, initb);
  scan_p3<<<512, 256, 0, stream>>>(gapre, ubf, lam, initb, conc);
  // 6. mixer GEMM + fused velocity/x_new epilogue: mixer=x_new, out1=velocity
  bgemm3_k<1 | 16><<<dim3(4, 32), 512, 0, stream>>>(conc, WoT, mixer, Mm, 1024, 2048,
      b_out, nullptr, velocity, x, log_beta, out1);
  // 8. normed = rmsnorm(x_new) (bf16)
  rmsnorm_bf_k<<<Mm, 256, 0, stream>>>(mixer, ffn_w, nrmbf);
  // 9. mid = gelu(normed @ W_ff1 + b_ff1) (bf16)
  bgemm3_k<1 | 2 | 8><<<dim3(16, 32), 512, 0, stream>>>(nrmbf, Wf1T, midbf, Mm, 4096, 1024,
      b_ff1, nullptr, nullptr, nullptr, nullptr, nullptr);
  // 10. out0 = mid @ W_ff2 + b_ff2 + x_new (fp32)
  bgemm3_k<1 | 4><<<dim3(4, 32), 512, 0, stream>>>(midbf, Wf2T, out0, Mm, 1024, 4096,
      b_ff2, mixer, nullptr, nullptr, nullptr, nullptr);
}

// Round 5
// 587.345 us; speedup vs baseline: 1.2106x; 1.1123x over previous
//
#include <hip/hip_runtime.h>

// (B,S,D,K,F) = (4, 2048, 1024, 4, 4096)
static constexpr int Bb = 4;
static constexpr int Ss = 2048;
static constexpr int Dd = 1024;
static constexpr int Ff = 4096;
static constexpr int Mm = Bb * Ss;              // 8192 rows
static constexpr size_t ND = (size_t)Mm * Dd;   // 8388608
static constexpr int CH = 32;                   // scan chunks
static constexpr int CL = Ss / CH;              // chunk length 64

typedef __attribute__((ext_vector_type(8))) short short8;
typedef __attribute__((ext_vector_type(4))) float floatx4;

__device__ __forceinline__ unsigned f2bf(float f) {
  unsigned u = __builtin_bit_cast(unsigned, f);
  return (u + 0x7FFFu + ((u >> 16) & 1u)) >> 16;   // RNE
}
__device__ __forceinline__ float bf2f(unsigned bits) {
  return __builtin_bit_cast(float, bits << 16);
}
__device__ __forceinline__ void gload_lds16(const void* g, void* lds) {
  __builtin_amdgcn_global_load_lds((const __attribute__((address_space(1))) void*)g,
                                   (__attribute__((address_space(3))) void*)lds,
                                   16, 0, 0);
}
// fast sigmoid / tanh-gelu via hw v_exp_f32 + v_rcp_f32 (f32-accurate ~1e-6)
__device__ __forceinline__ float fsig(float x) {
  return __builtin_amdgcn_rcpf(1.0f + __expf(-x));
}
__device__ __forceinline__ float fgelu(float v) {
  float z = 1.5957691216057308f * fmaf(0.044715f * v, v * v, v);
  return v * __builtin_amdgcn_rcpf(1.0f + __expf(-z));
}

// ---------------- weight transpose + fp32->bf16: W[K][N] -> WT[N][K] --------
__global__ __launch_bounds__(256) void wconv_k(const float* __restrict__ W,
                                               unsigned short* __restrict__ WT,
                                               int K, int N) {
  __shared__ float tile[32][33];
  int tx = threadIdx.x & 31, ty = threadIdx.x >> 5;
  int bx = blockIdx.x * 32, by = blockIdx.y * 32;
#pragma unroll
  for (int i = 0; i < 32; i += 8)
    tile[ty + i][tx] = W[(size_t)(by + ty + i) * N + bx + tx];
  __syncthreads();
#pragma unroll
  for (int i = 0; i < 32; i += 8)
    WT[(size_t)(bx + ty + i) * K + by + tx] = (unsigned short)f2bf(tile[tx][ty + i]);
}

// ---------------- RMSNorm: fp32 in, bf16 out --------------------------------
__global__ __launch_bounds__(256) void rmsnorm_bf_k(const float* __restrict__ x,
                                                    const float* __restrict__ w,
                                                    unsigned short* __restrict__ out) {
  int row = blockIdx.x;
  const float4* xr = (const float4*)(x + (size_t)row * Dd);
  int t = threadIdx.x;
  float4 v = xr[t];
  float ss = v.x * v.x + v.y * v.y + v.z * v.z + v.w * v.w;
#pragma unroll
  for (int off = 32; off > 0; off >>= 1) ss += __shfl_down(ss, off, 64);
  __shared__ float sb[4];
  if ((t & 63) == 0) sb[t >> 6] = ss;
  __syncthreads();
  float tot = sb[0] + sb[1] + sb[2] + sb[3];
  float sc = rsqrtf(tot * (1.0f / (float)Dd) + 1e-6f);
  float4 wv = ((const float4*)w)[t];
  unsigned lo = f2bf(v.x * sc * wv.x) | (f2bf(v.y * sc * wv.y) << 16);
  unsigned hi = f2bf(v.z * sc * wv.z) | (f2bf(v.w * sc * wv.w) << 16);
  *(uint2*)(out + (size_t)row * Dd + t * 4) = make_uint2(lo, hi);
}

// ---------------- Causal depthwise conv (bf16 in/out) -> concat[:,0:D] ------
__global__ __launch_bounds__(256) void conv_k(const unsigned short* __restrict__ xn,
                                              const float* __restrict__ kern,
                                              const float* __restrict__ bias,
                                              unsigned short* __restrict__ outC) {
  size_t q = (size_t)blockIdx.x * 256 + threadIdx.x;  // over ND/4
  size_t i = q * 4;
  int d = (int)(i & (Dd - 1));
  int m = (int)(i >> 10);
  int t = m & (Ss - 1);
  float acc[4];
#pragma unroll
  for (int j = 0; j < 4; j++) acc[j] = bias[d + j];
#pragma unroll
  for (int k = 0; k < 4; k++) {
    if (t >= k) {
      uint2 xv = *(const uint2*)(xn + i - (size_t)k * Dd);
      float x0 = bf2f(xv.x & 0xFFFF), x1 = bf2f(xv.x >> 16);
      float x2 = bf2f(xv.y & 0xFFFF), x3 = bf2f(xv.y >> 16);
      acc[0] = fmaf(kern[(d + 0) * 4 + k], x0, acc[0]);
      acc[1] = fmaf(kern[(d + 1) * 4 + k], x1, acc[1]);
      acc[2] = fmaf(kern[(d + 2) * 4 + k], x2, acc[2]);
      acc[3] = fmaf(kern[(d + 3) * 4 + k], x3, acc[3]);
    }
  }
  unsigned lo = f2bf(acc[0]) | (f2bf(acc[1]) << 16);
  unsigned hi = f2bf(acc[2]) | (f2bf(acc[3]) << 16);
  *(uint2*)(outC + (size_t)m * (2 * Dd) + d) = make_uint2(lo, hi);
}

// ---------------- bf16 MFMA GEMM v4: m201-style 8-phase 256x256 template ----
// (unchanged from round 4 -- measured: FETCH collapse, 0 bank conflicts,
// VGPR=128 no spill, ~39% per-active-CU MFMA rate)
// MODE bits: 1=+bias[col], 2=gelu, 4=+extra (fp32), 8=bf16 out, 16=velocity
template <int MODE>
__global__ __launch_bounds__(512, 2) void bgemm3_k(const unsigned short* __restrict__ A,
                                                   const unsigned short* __restrict__ BT,
                                                   void* __restrict__ Cout,
                                                   int M, int N, int K,
                                                   const float* __restrict__ bias,
                                                   const float* __restrict__ extra,
                                                   const float* __restrict__ vel_in,
                                                   const float* __restrict__ x_in,
                                                   const float* __restrict__ log_beta,
                                                   float* __restrict__ vel_out) {
  __shared__ unsigned short LA[2][256 * 64];   // 64 KiB
  __shared__ unsigned short LB[2][256 * 64];   // 64 KiB
  const int tid = threadIdx.x;
  const int wid = tid >> 6, lane = tid & 63;
  const int wm = wid >> 2, wn = wid & 3;       // 2M x 4N wave grid
  const int r = lane & 15, quad = lane >> 4, r7 = lane & 7;

  // ---- chunked XCD swizzle (nwg % 8 == 0 for all shapes)
  const int gx = gridDim.x;
  int id = blockIdx.y * gx + blockIdx.x;
  const int nwg = gx * gridDim.y;
  id = (id & 7) * (nwg >> 3) + (id >> 3);
  const int bm = (id / gx) * 256, bn = (id % gx) * 256;
  const int NIT = K >> 7;                      // iterations of 2 K-tiles

  const int lrow = lane >> 3;
  const int sblk = (lane & 7) ^ lrow;          // pre-swizzled 16B block index
  const unsigned short* AsrcB = A  + (size_t)(bm + lrow) * K + sblk * 8;
  const unsigned short* BsrcB = BT + (size_t)(bn + lrow) * K + sblk * 8;

  const int aB = wm * 8192 + r * 64;
  const int bB = wn * 4096 + r * 64;
  const int kq0 = (quad ^ r7) * 8;
  const int kq1 = ((4 + quad) ^ r7) * 8;

  floatx4 acc[8][4];
#pragma unroll
  for (int i = 0; i < 8; i++)
#pragma unroll
    for (int j = 0; j < 4; j++) acc[i][j] = (floatx4){0.f, 0.f, 0.f, 0.f};

#define STG_A(bq, k0, h, s)                                                           \
  gload_lds16(AsrcB + (size_t)((h) * 128 + (s) * 64 + wid * 8) * K + (k0),            \
              (void*)&LA[bq][((h) * 128 + (s) * 64 + wid * 8) * 64])
#define STG_B(bq, k0, h, s)                                                           \
  gload_lds16(BsrcB + (size_t)((h) * 128 + (s) * 64 + wid * 8) * K + (k0),            \
              (void*)&LB[bq][((h) * 128 + (s) * 64 + wid * 8) * 64])
#define RDA(il, IH, buf)                                                              \
  aF[il][0] = *(const short8*)&LA[buf][aB + (IH) * 4096 + (il) * 1024 + kq0];         \
  aF[il][1] = *(const short8*)&LA[buf][aB + (IH) * 4096 + (il) * 1024 + kq1]
#define RDB(BF, jl, jg, buf)                                                          \
  BF[jl][0] = *(const short8*)&LB[buf][bB + (jg) * 1024 + kq0];                       \
  BF[jl][1] = *(const short8*)&LB[buf][bB + (jg) * 1024 + kq1]
#define MM2(il, jl, BF, IH, JH)                                                       \
  acc[(IH) * 4 + (il)][(JH) * 2 + (jl)] = __builtin_amdgcn_mfma_f32_16x16x32_bf16(    \
      BF[jl][0], aF[il][0], acc[(IH) * 4 + (il)][(JH) * 2 + (jl)], 0, 0, 0);          \
  acc[(IH) * 4 + (il)][(JH) * 2 + (jl)] = __builtin_amdgcn_mfma_f32_16x16x32_bf16(    \
      BF[jl][1], aF[il][1], acc[(IH) * 4 + (il)][(JH) * 2 + (jl)], 0, 0, 0)
#define MQUAD(BF, IH, JH)                                                             \
  MM2(0, 0, BF, IH, JH); MM2(0, 1, BF, IH, JH); MM2(1, 0, BF, IH, JH);                \
  MM2(1, 1, BF, IH, JH); MM2(2, 0, BF, IH, JH); MM2(2, 1, BF, IH, JH);                \
  MM2(3, 0, BF, IH, JH); MM2(3, 1, BF, IH, JH)
#define BAR() __builtin_amdgcn_s_barrier()
#define LGK0()                                                                        \
  asm volatile("s_waitcnt lgkmcnt(0)" ::: "memory");                                  \
  __builtin_amdgcn_sched_barrier(0)
#define PRIO(x) __builtin_amdgcn_s_setprio(x)

  // ---- prologue: tile0 (A+B) -> buf0, tile1 B -> buf1; drain tile0 only.
  STG_A(0, 0, 0, 0); STG_A(0, 0, 0, 1); STG_A(0, 0, 1, 0); STG_A(0, 0, 1, 1);
  STG_B(0, 0, 0, 0); STG_B(0, 0, 0, 1); STG_B(0, 0, 1, 0); STG_B(0, 0, 1, 1);
  STG_B(1, 64, 0, 0); STG_B(1, 64, 0, 1); STG_B(1, 64, 1, 0); STG_B(1, 64, 1, 1);
  asm volatile("s_waitcnt vmcnt(4)" ::: "memory");
  BAR();
  __builtin_amdgcn_sched_barrier(0);

  for (int it = 0; it < NIT; ++it) {
    const int T = 2 * it;
    const int pf = (it + 1 < NIT);
    const int kA1 = (T + 1) << 6;
    const int k2 = (T + 2) << 6, k3 = (T + 3) << 6;
    short8 aF[4][2], b0[2][2], b1[2][2];

    // p0
    STG_A(1, kA1, 0, 0); STG_A(1, kA1, 0, 1);
    RDA(0, 0, 0); RDA(1, 0, 0); RDA(2, 0, 0); RDA(3, 0, 0);
    RDB(b0, 0, 0, 0); RDB(b0, 1, 1, 0);
    BAR(); LGK0();
    PRIO(1); MQUAD(b0, 0, 0); PRIO(0);
    BAR();

    // p1
    STG_A(1, kA1, 1, 0); STG_A(1, kA1, 1, 1);
    RDB(b1, 0, 2, 0); RDB(b1, 1, 3, 0);
    BAR(); LGK0();
    PRIO(1); MQUAD(b1, 0, 1); PRIO(0);
    BAR();

    // p2
    if (pf) { STG_B(0, k2, 0, 0); STG_B(0, k2, 0, 1); }
    RDA(0, 1, 0); RDA(1, 1, 0); RDA(2, 1, 0); RDA(3, 1, 0);
    BAR(); LGK0();
    PRIO(1); MQUAD(b0, 1, 0); PRIO(0);
    BAR();

    // p3 ; GATE 1
    if (pf) { STG_B(0, k2, 1, 0); STG_B(0, k2, 1, 1); }
    BAR();
    PRIO(1); MQUAD(b1, 1, 1); PRIO(0);
    if (pf) asm volatile("s_waitcnt vmcnt(4)" ::: "memory");
    else    asm volatile("s_waitcnt vmcnt(0)" ::: "memory");
    BAR();
    __builtin_amdgcn_sched_barrier(0);

    // p4
    if (pf) { STG_A(0, k2, 0, 0); STG_A(0, k2, 0, 1); }
    RDA(0, 0, 1); RDA(1, 0, 1); RDA(2, 0, 1); RDA(3, 0, 1);
    RDB(b0, 0, 0, 1); RDB(b0, 1, 1, 1);
    BAR(); LGK0();
    PRIO(1); MQUAD(b0, 0, 0); PRIO(0);
    BAR();

    // p5
    if (pf) { STG_A(0, k2, 1, 0); STG_A(0, k2, 1, 1); }
    RDB(b1, 0, 2, 1); RDB(b1, 1, 3, 1);
    BAR(); LGK0();
    PRIO(1); MQUAD(b1, 0, 1); PRIO(0);
    BAR();

    // p6
    if (pf) { STG_B(1, k3, 0, 0); STG_B(1, k3, 0, 1); }
    RDA(0, 1, 1); RDA(1, 1, 1); RDA(2, 1, 1); RDA(3, 1, 1);
    BAR(); LGK0();
    PRIO(1); MQUAD(b0, 1, 0); PRIO(0);
    BAR();

    // p7 ; GATE 2 (skipped on final iter)
    if (pf) { STG_B(1, k3, 1, 0); STG_B(1, k3, 1, 1); }
    BAR();
    PRIO(1); MQUAD(b1, 1, 1); PRIO(0);
    if (pf) {
      asm volatile("s_waitcnt vmcnt(4)" ::: "memory");
      BAR();
      __builtin_amdgcn_sched_barrier(0);
    }
  }
#undef STG_A
#undef STG_B
#undef RDA
#undef RDB
#undef MM2
#undef MQUAD

  // acc[i][j][0..3] = C[row = bm+wm*128+i*16+r][col = bn+wn*64+j*16+quad*4 +0..3]
#pragma unroll
  for (int i = 0; i < 8; i++) {
    int rowg = bm + wm * 128 + i * 16 + r;
#pragma unroll
    for (int j = 0; j < 4; j++) {
      int colg = bn + wn * 64 + j * 16 + quad * 4;
      size_t idx = (size_t)rowg * N + colg;
      float v0 = acc[i][j][0], v1 = acc[i][j][1], v2 = acc[i][j][2], v3 = acc[i][j][3];
      if (MODE & 1) {
        float4 bv = *(const float4*)(bias + colg);
        v0 += bv.x; v1 += bv.y; v2 += bv.z; v3 += bv.w;
      }
      if (MODE & 2) {
        v0 = fgelu(v0); v1 = fgelu(v1); v2 = fgelu(v2); v3 = fgelu(v3);
      }
      if (MODE & 4) {
        float4 ev = *(const float4*)(extra + idx);
        v0 += ev.x; v1 += ev.y; v2 += ev.z; v3 += ev.w;
      }
      if (MODE & 16) {
        float4 lb = *(const float4*)(log_beta + colg);
        float4 vi = *(const float4*)(vel_in + idx);
        float4 xi = *(const float4*)(x_in + idx);
        float4 vn;
        vn.x = fmaf(fsig(lb.x), vi.x, v0);
        vn.y = fmaf(fsig(lb.y), vi.y, v1);
        vn.z = fmaf(fsig(lb.z), vi.z, v2);
        vn.w = fmaf(fsig(lb.w), vi.w, v3);
        *(float4*)(vel_out + idx) = vn;
        v0 = xi.x + vn.x; v1 = xi.y + vn.y; v2 = xi.z + vn.z; v3 = xi.w + vn.w;
      }
      if (MODE & 8) {
        uint2 pk;
        pk.x = f2bf(v0) | (f2bf(v1) << 16);
        pk.y = f2bf(v2) | (f2bf(v3) << 16);
        *(uint2*)((unsigned short*)Cout + idx) = pk;
      } else {
        float4 o; o.x = v0; o.y = v1; o.z = v2; o.w = v3;
        *(float4*)((float*)Cout + idx) = o;
      }
    }
  }
}

// ---------------- bf16 MFMA GEMM v5: BN=128 8-phase variant (full chip at
// N=1024). BM=256, BN=128, BK=64, 512 thr = 8 waves as 4M x 2N (wave tile
// 64x64, acc[4][4] = 64 VGPR -- best LDS-read/MFMA at this width). LDS:
// 2 x (A 32K + B 16K) = 96 KiB. Same 8-phase skeleton as v4; B-tile is half
// so B stage slots issue 1 gload instead of 2; gates become vmcnt(2) (FIFO:
// keeps only the 2 youngest B loads in flight; forces the A tile consumed
// next phase -- same safety argument as v4's vmcnt(4)). Per phase: 8 MFMA.
// Phase->quadrant map per K-tile: p0 (IH0,JH0), p1 (IH0,JH1), p2 (IH1,JH0),
// p3 (IH1,JH1); reads: p0 aF(IH0)+b0(JH0), p1 b1(JH1), p2 aF(IH1), p3 none.
template <int MODE>
__global__ __launch_bounds__(512, 2) void bgemm4_k(const unsigned short* __restrict__ A,
                                                   const unsigned short* __restrict__ BT,
                                                   void* __restrict__ Cout,
                                                   int M, int N, int K,
                                                   const float* __restrict__ bias,
                                                   const float* __restrict__ extra,
                                                   const float* __restrict__ vel_in,
                                                   const float* __restrict__ x_in,
                                                   const float* __restrict__ log_beta,
                                                   float* __restrict__ vel_out) {
  __shared__ unsigned short LA[2][256 * 64];   // 64 KiB
  __shared__ unsigned short LB[2][128 * 64];   // 32 KiB
  const int tid = threadIdx.x;
  const int wid = tid >> 6, lane = tid & 63;
  const int wm = wid >> 1, wn = wid & 1;       // 4M x 2N wave grid
  const int r = lane & 15, quad = lane >> 4, r7 = lane & 7;

  const int gx = gridDim.x;
  int id = blockIdx.y * gx + blockIdx.x;
  const int nwg = gx * gridDim.y;
  id = (id & 7) * (nwg >> 3) + (id >> 3);
  const int bm = (id / gx) * 256, bn = (id % gx) * 128;
  const int NIT = K >> 7;

  const int lrow = lane >> 3;
  const int sblk = (lane & 7) ^ lrow;
  const unsigned short* AsrcB = A  + (size_t)(bm + lrow) * K + sblk * 8;
  const unsigned short* BsrcB = BT + (size_t)(bn + lrow) * K + sblk * 8;

  const int aB = wm * 4096 + r * 64;           // wm*64 rows
  const int bB = wn * 4096 + r * 64;           // wn*64 rows
  const int kq0 = (quad ^ r7) * 8;
  const int kq1 = ((4 + quad) ^ r7) * 8;

  floatx4 acc[4][4];
#pragma unroll
  for (int i = 0; i < 4; i++)
#pragma unroll
    for (int j = 0; j < 4; j++) acc[i][j] = (floatx4){0.f, 0.f, 0.f, 0.f};

#define STG_A4(bq, k0, h, s)                                                          \
  gload_lds16(AsrcB + (size_t)((h) * 128 + (s) * 64 + wid * 8) * K + (k0),            \
              (void*)&LA[bq][((h) * 128 + (s) * 64 + wid * 8) * 64])
#define STG_B4(bq, k0, s)                                                             \
  gload_lds16(BsrcB + (size_t)((s) * 64 + wid * 8) * K + (k0),                        \
              (void*)&LB[bq][((s) * 64 + wid * 8) * 64])
#define RDA4(IH, buf)                                                                 \
  aF[0][0] = *(const short8*)&LA[buf][aB + (IH) * 2048 + kq0];                        \
  aF[0][1] = *(const short8*)&LA[buf][aB + (IH) * 2048 + kq1];                        \
  aF[1][0] = *(const short8*)&LA[buf][aB + (IH) * 2048 + 1024 + kq0];                 \
  aF[1][1] = *(const short8*)&LA[buf][aB + (IH) * 2048 + 1024 + kq1]
#define RDB4(BF, JH, buf)                                                             \
  BF[0][0] = *(const short8*)&LB[buf][bB + (JH) * 2048 + kq0];                        \
  BF[0][1] = *(const short8*)&LB[buf][bB + (JH) * 2048 + kq1];                        \
  BF[1][0] = *(const short8*)&LB[buf][bB + (JH) * 2048 + 1024 + kq0];                 \
  BF[1][1] = *(const short8*)&LB[buf][bB + (JH) * 2048 + 1024 + kq1]
#define MM24(il, jl, BF, IH, JH)                                                      \
  acc[(IH) * 2 + (il)][(JH) * 2 + (jl)] = __builtin_amdgcn_mfma_f32_16x16x32_bf16(    \
      BF[jl][0], aF[il][0], acc[(IH) * 2 + (il)][(JH) * 2 + (jl)], 0, 0, 0);          \
  acc[(IH) * 2 + (il)][(JH) * 2 + (jl)] = __builtin_amdgcn_mfma_f32_16x16x32_bf16(    \
      BF[jl][1], aF[il][1], acc[(IH) * 2 + (il)][(JH) * 2 + (jl)], 0, 0, 0)
#define MQ4(BF, IH, JH)                                                               \
  MM24(0, 0, BF, IH, JH); MM24(0, 1, BF, IH, JH);                                     \
  MM24(1, 0, BF, IH, JH); MM24(1, 1, BF, IH, JH)

  // ---- prologue: tile0 A+B -> buf0, tile1 B -> buf1; drain tile0 (keep B1).
  STG_A4(0, 0, 0, 0); STG_A4(0, 0, 0, 1); STG_A4(0, 0, 1, 0); STG_A4(0, 0, 1, 1);
  STG_B4(0, 0, 0); STG_B4(0, 0, 1);
  STG_B4(1, 64, 0); STG_B4(1, 64, 1);
  asm volatile("s_waitcnt vmcnt(2)" ::: "memory");
  BAR();
  __builtin_amdgcn_sched_barrier(0);

  for (int it = 0; it < NIT; ++it) {
    const int T = 2 * it;
    const int pf = (it + 1 < NIT);
    const int kA1 = (T + 1) << 6;
    const int k2 = (T + 2) << 6, k3 = (T + 3) << 6;
    short8 aF[2][2], b0[2][2], b1[2][2];

    // p0: stage A(T+1)h0->buf1 ; read aF(IH0)+b0(JH0) of T; MFMA (IH0,JH0)
    STG_A4(1, kA1, 0, 0); STG_A4(1, kA1, 0, 1);
    RDA4(0, 0); RDB4(b0, 0, 0);
    BAR(); LGK0();
    PRIO(1); MQ4(b0, 0, 0); PRIO(0);
    BAR();

    // p1: stage A(T+1)h1->buf1 ; read b1(JH1); MFMA (IH0,JH1)
    STG_A4(1, kA1, 1, 0); STG_A4(1, kA1, 1, 1);
    RDB4(b1, 1, 0);
    BAR(); LGK0();
    PRIO(1); MQ4(b1, 0, 1); PRIO(0);
    BAR();

    // p2: stage B(T+2)s0->buf0 ; read aF(IH1); MFMA (IH1,JH0)
    if (pf) STG_B4(0, k2, 0);
    RDA4(1, 0);
    BAR(); LGK0();
    PRIO(1); MQ4(b0, 1, 0); PRIO(0);
    BAR();

    // p3: stage B(T+2)s1->buf0 ; MFMA (IH1,JH1) ; GATE 1
    if (pf) STG_B4(0, k2, 1);
    BAR();
    PRIO(1); MQ4(b1, 1, 1); PRIO(0);
    if (pf) asm volatile("s_waitcnt vmcnt(2)" ::: "memory");
    else    asm volatile("s_waitcnt vmcnt(0)" ::: "memory");
    BAR();
    __builtin_amdgcn_sched_barrier(0);

    // p4: stage A(T+2)h0->buf0 ; read aF(IH0)+b0(JH0) of T+1 (buf1)
    if (pf) { STG_A4(0, k2, 0, 0); STG_A4(0, k2, 0, 1); }
    RDA4(0, 1); RDB4(b0, 0, 1);
    BAR(); LGK0();
    PRIO(1); MQ4(b0, 0, 0); PRIO(0);
    BAR();

    // p5: stage A(T+2)h1->buf0 ; read b1(JH1); MFMA (IH0,JH1)
    if (pf) { STG_A4(0, k2, 1, 0); STG_A4(0, k2, 1, 1); }
    RDB4(b1, 1, 1);
    BAR(); LGK0();
    PRIO(1); MQ4(b1, 0, 1); PRIO(0);
    BAR();

    // p6: stage B(T+3)s0->buf1 ; read aF(IH1); MFMA (IH1,JH0)
    if (pf) STG_B4(1, k3, 0);
    RDA4(1, 1);
    BAR(); LGK0();
    PRIO(1); MQ4(b0, 1, 0); PRIO(0);
    BAR();

    // p7: stage B(T+3)s1->buf1 ; MFMA (IH1,JH1) ; GATE 2 (skip on final iter)
    if (pf) STG_B4(1, k3, 1);
    BAR();
    PRIO(1); MQ4(b1, 1, 1); PRIO(0);
    if (pf) {
      asm volatile("s_waitcnt vmcnt(2)" ::: "memory");
      BAR();
      __builtin_amdgcn_sched_barrier(0);
    }
  }
#undef STG_A4
#undef STG_B4
#undef RDA4
#undef RDB4
#undef MM24
#undef MQ4
#undef BAR
#undef LGK0
#undef PRIO

  // acc[i][j][0..3] = C[row = bm+wm*64+i*16+r][col = bn+wn*64+j*16+quad*4 +0..3]
#pragma unroll
  for (int i = 0; i < 4; i++) {
    int rowg = bm + wm * 64 + i * 16 + r;
#pragma unroll
    for (int j = 0; j < 4; j++) {
      int colg = bn + wn * 64 + j * 16 + quad * 4;
      size_t idx = (size_t)rowg * N + colg;
      float v0 = acc[i][j][0], v1 = acc[i][j][1], v2 = acc[i][j][2], v3 = acc[i][j][3];
      if (MODE & 1) {
        float4 bv = *(const float4*)(bias + colg);
        v0 += bv.x; v1 += bv.y; v2 += bv.z; v3 += bv.w;
      }
      if (MODE & 2) {
        v0 = fgelu(v0); v1 = fgelu(v1); v2 = fgelu(v2); v3 = fgelu(v3);
      }
      if (MODE & 4) {
        float4 ev = *(const float4*)(extra + idx);
        v0 += ev.x; v1 += ev.y; v2 += ev.z; v3 += ev.w;
      }
      if (MODE & 16) {
        float4 lb = *(const float4*)(log_beta + colg);
        float4 vi = *(const float4*)(vel_in + idx);
        float4 xi = *(const float4*)(x_in + idx);
        float4 vn;
        vn.x = fmaf(fsig(lb.x), vi.x, v0);
        vn.y = fmaf(fsig(lb.y), vi.y, v1);
        vn.z = fmaf(fsig(lb.z), vi.z, v2);
        vn.w = fmaf(fsig(lb.w), vi.w, v3);
        *(float4*)(vel_out + idx) = vn;
        v0 = xi.x + vn.x; v1 = xi.y + vn.y; v2 = xi.z + vn.z; v3 = xi.w + vn.w;
      }
      if (MODE & 8) {
        uint2 pk;
        pk.x = f2bf(v0) | (f2bf(v1) << 16);
        pk.y = f2bf(v2) | (f2bf(v3) << 16);
        *(uint2*)((unsigned short*)Cout + idx) = pk;
      } else {
        float4 o; o.x = v0; o.y = v1; o.z = v2; o.w = v3;
        *(float4*)((float*)Cout + idx) = o;
      }
    }
  }
}

// ---------------- scan phase 1: gating + per-chunk (A, h_local) -------------
__global__ __launch_bounds__(256) void scan_p1(const unsigned short* __restrict__ gapre,
                                               const unsigned short* __restrict__ xn,
                                               const float* __restrict__ lam,
                                               unsigned short* __restrict__ ub,
                                               float* __restrict__ carryA,
                                               float* __restrict__ carryH) {
  int g = blockIdx.x * 256 + threadIdx.x;    // 0..131071
  int e = g & (Dd - 1);
  int bc = g >> 10;
  int b = bc & 3;
  int c = bc >> 2;
  float l = lam[e];
  float sp = fmaxf(l, 0.0f) + log1pf(__expf(-fabsf(l)));
  float m8sp = -8.0f * sp;
  size_t m0 = (size_t)b * Ss + (size_t)c * CL;
  float A = 1.0f, h = 0.0f;
#pragma unroll 4
  for (int t = 0; t < CL; t++) {
    size_t m = m0 + t;
    float gp = bf2f(gapre[m * 2048 + e]);
    float ap = bf2f(gapre[m * 2048 + 1024 + e]);
    float xv = bf2f(xn[m * Dd + e]);
    float a = __expf(m8sp * fsig(ap));
    float u = sqrtf(fmaxf(1.0f - a * a, 0.0f)) * fsig(gp) * xv;
    ub[m * Dd + e] = (unsigned short)f2bf(u);
    A *= a;
    h = fmaf(a, h, u);
  }
  carryA[c * 4096 + b * 1024 + e] = A;
  carryH[c * 4096 + b * 1024 + e] = h;
}

// ---------------- scan phase 2: scan carries -> per-chunk init state --------
__global__ __launch_bounds__(256) void scan_p2(const float* __restrict__ carryA,
                                               const float* __restrict__ carryH,
                                               float* __restrict__ init) {
  int ch = blockIdx.x * 256 + threadIdx.x;   // 0..4095
  float H = 0.0f;
#pragma unroll
  for (int c = 0; c < CH; c++) {
    init[c * 4096 + ch] = H;
    H = fmaf(carryA[c * 4096 + ch], H, carryH[c * 4096 + ch]);
  }
}

// ---------------- scan phase 3: rescan chunk with init -> concat[:,D:2D] ----
__global__ __launch_bounds__(256) void scan_p3(const unsigned short* __restrict__ gapre,
                                               const unsigned short* __restrict__ ub,
                                               const float* __restrict__ lam,
                                               const float* __restrict__ init,
                                               unsigned short* __restrict__ outC) {
  int g = blockIdx.x * 256 + threadIdx.x;
  int e = g & (Dd - 1);
  int bc = g >> 10;
  int b = bc & 3;
  int c = bc >> 2;
  float l = lam[e];
  float sp = fmaxf(l, 0.0f) + log1pf(__expf(-fabsf(l)));
  float m8sp = -8.0f * sp;
  size_t m0 = (size_t)b * Ss + (size_t)c * CL;
  float h = init[c * 4096 + b * 1024 + e];
#pragma unroll 4
  for (int t = 0; t < CL; t++) {
    size_t m = m0 + t;
    float ap = bf2f(gapre[m * 2048 + 1024 + e]);
    float a = __expf(m8sp * fsig(ap));
    float u = bf2f(ub[m * Dd + e]);
    h = fmaf(a, h, u);
    outC[m * (2 * Dd) + Dd + e] = (unsigned short)f2bf(h);
  }
}

extern "C" void kernel_launch(void* const* d_in, const int* in_sizes, int n_in,
                              void* d_out, int out_size, void* d_ws, size_t ws_size,
                              hipStream_t stream) {
  const float* x        = (const float*)d_in[0];
  const float* velocity = (const float*)d_in[1];
  const float* pre_w    = (const float*)d_in[2];
  const float* conv_w   = (const float*)d_in[3];
  const float* conv_b   = (const float*)d_in[4];
  const float* W_gate   = (const float*)d_in[5];
  const float* W_a      = (const float*)d_in[6];
  const float* lam      = (const float*)d_in[7];
  const float* W_out    = (const float*)d_in[8];
  const float* b_out    = (const float*)d_in[9];
  const float* log_beta = (const float*)d_in[10];
  const float* ffn_w    = (const float*)d_in[11];
  const float* W_ff1    = (const float*)d_in[12];
  const float* b_ff1    = (const float*)d_in[13];
  const float* W_ff2    = (const float*)d_in[14];
  const float* b_ff2    = (const float*)d_in[15];

  float* out0 = (float*)d_out;
  float* out1 = out0 + ND;

  // ---- workspace (byte offsets), lifetime-aliased; peak 152 MB ----
  const size_t MB = 1024 * 1024;
  char* ws = (char*)d_ws;
  unsigned short* WgaT  = (unsigned short*)ws;               // 2048x1024 [0,4) (gate|a)
  unsigned short* WoT   = WgaT + (size_t)2 * 1024 * 1024;    // [4,8)
  unsigned short* Wf1T  = WoT + (size_t)2 * 1024 * 1024;     // [8,16)
  unsigned short* Wf2T  = Wf1T + (size_t)4 * 1024 * 1024;    // [16,24)
  float*          mixer = (float*)(ws + 24 * MB);            // 32 MB [24,56) — x_new
  float*          carA  = (float*)(ws + 24 * MB);            // overlay (pre-step-6)
  float*          carH  = (float*)(ws + 24 * MB + 512 * 1024);
  float*          initb = (float*)(ws + 25 * MB);
  unsigned short* conc  = (unsigned short*)(ws + 56 * MB);   // 32 MB [56,88)
  unsigned short* gapre = (unsigned short*)(ws + 88 * MB);   // 32 MB [88,120)
  unsigned short* xnbf  = (unsigned short*)(ws + 120 * MB);  // 16 MB [120,136)
  unsigned short* ubf   = (unsigned short*)(ws + 136 * MB);  // 16 MB [136,152)
  unsigned short* midbf = (unsigned short*)(ws + 88 * MB);   // 64 MB overlay [88,152)
  unsigned short* nrmbf = (unsigned short*)(ws + 56 * MB);   // overlay conc

  const int EB = 256;
  const int egrid4 = (int)(ND / 4 / EB);

  // 0. weight transpose + bf16 convert (gate|a combined, contiguous)
  wconv_k<<<dim3(32, 32),  256, 0, stream>>>(W_gate, WgaT, 1024, 1024);
  wconv_k<<<dim3(32, 32),  256, 0, stream>>>(W_a,    WgaT + (size_t)1024 * 1024, 1024, 1024);
  wconv_k<<<dim3(32, 64),  256, 0, stream>>>(W_out,  WoT, 2048, 1024);
  wconv_k<<<dim3(128, 32), 256, 0, stream>>>(W_ff1,  Wf1T, 1024, 4096);
  wconv_k<<<dim3(32, 128), 256, 0, stream>>>(W_ff2,  Wf2T, 4096, 1024);
  // 1. x_norm (bf16)
  rmsnorm_bf_k<<<Mm, 256, 0, stream>>>(x, pre_w, xnbf);
  // 2. conv -> concat[:, 0:D]
  conv_k<<<egrid4, EB, 0, stream>>>(xnbf, conv_w, conv_b, conc);
  // 3. fused gate_pre|a_pre GEMM (N=2048, bf16 out) — 256 blocks, full chip
  bgemm3_k<8><<<dim3(8, 32), 512, 0, stream>>>(xnbf, WgaT, gapre, Mm, 2048, 1024,
      nullptr, nullptr, nullptr, nullptr, nullptr, nullptr);
  // 4-5. chunked scan (gating fused into P1) -> concat[:, D:2D]
  scan_p1<<<512, 256, 0, stream>>>(gapre, xnbf, lam, ubf, carA, carH);
  scan_p2<<<16, 256, 0, stream>>>(carA, carH, initb);
  scan_p3<<<512, 256, 0, stream>>>(gapre, ubf, lam, initb, conc);
  // 6. mixer GEMM (N=1024) -> BN=128 variant, 256 blocks full chip
  bgemm4_k<1 | 16><<<dim3(8, 32), 512, 0, stream>>>(conc, WoT, mixer, Mm, 1024, 2048,
      b_out, nullptr, velocity, x, log_beta, out1);
  // 8. normed = rmsnorm(x_new) (bf16)
  rmsnorm_bf_k<<<Mm, 256, 0, stream>>>(mixer, ffn_w, nrmbf);
  // 9. mid = gelu(normed @ W_ff1 + b_ff1) (bf16) — 512 blocks
  bgemm3_k<1 | 2 | 8><<<dim3(16, 32), 512, 0, stream>>>(nrmbf, Wf1T, midbf, Mm, 4096, 1024,
      b_ff1, nullptr, nullptr, nullptr, nullptr, nullptr);
  // 10. out0 = mid @ W_ff2 + b_ff2 + x_new (fp32, N=1024) -> BN=128 variant
  bgemm4_k<1 | 4><<<dim3(8, 32), 512, 0, stream>>>(midbf, Wf2T, out0, Mm, 1024, 4096,
      b_ff2, mixer, nullptr, nullptr, nullptr, nullptr);
}